// Round 2
// baseline (3274.924 us; speedup 1.0000x reference)
//
#include <hip/hip_runtime.h>

#define DIM 64
#define NC 50

__device__ __forceinline__ float sp_f(float x){
  // torch Softplus(beta=0.5, threshold=14): 2*log(1+exp(0.5x)), linear when 0.5x>14
  float e = __expf(0.5f*x);
  float s = 2.0f*__logf(1.0f+e);
  return x > 28.0f ? x : s;
}

// ---------------- prep kernels ----------------

__global__ void flag_zero_kernel(unsigned char* flag, int E){
  int id = blockIdx.x*256 + threadIdx.x;
  if (id < E) flag[id] = 0;
}

__global__ void flag_set_kernel(const int* __restrict__ sel, unsigned char* flag, int K){
  int id = blockIdx.x*256 + threadIdx.x;
  if (id < K) flag[sel[id]] = 1;
}

__global__ void prep_transpose_kernel(const float* __restrict__ cf_w2,
                                      const float* __restrict__ nl3_w,
                                      const float* __restrict__ et1_w,
                                      float* __restrict__ w2t,
                                      float* __restrict__ nl3t,
                                      float* __restrict__ et1t){
  int id = blockIdx.x*256 + threadIdx.x;
  if (id < 3*4096){
    int i = id >> 12, r = id & 4095;
    int k = r >> 6, j = r & 63;
    // w2t[i][k][j] = cf_w2[i][j][k]
    w2t[id]  = cf_w2[i*4096 + j*64 + k];
    nl3t[id] = nl3_w[i*4096 + j*64 + k];
  }
  if (id < 128*64){
    int k = id >> 6, j = id & 63;
    // et1t[k][j] = et1_w[j][k]   (et1_w is [64][128])
    et1t[id] = et1_w[j*128 + k];
  }
}

__global__ void node_init_kernel(const float* __restrict__ emb,
                                 const int* __restrict__ node_type,
                                 float* __restrict__ node, int N){
  long id = (long)blockIdx.x*256 + threadIdx.x;
  if (id < (long)N*64){
    int n = (int)(id >> 6), j = (int)(id & 63);
    node[id] = emb[(long)node_type[n]*64 + j];
  }
}

// ---------------- node-side GEMMs ----------------

// new_node[n][j] = sum_k node[n][k] * w1[j][k]   (w1 = conv_w1[i], [64][64] row-major)
__global__ __launch_bounds__(64) void new_node_kernel(const float* __restrict__ node,
                                                      const float* __restrict__ w1,
                                                      float* __restrict__ out, int N){
  int lane = threadIdx.x;
  long n = (long)blockIdx.x*64 + lane;
  if (n >= N) return;
  float x[DIM];
  const float4* xr = (const float4*)(node + n*64);
  #pragma unroll
  for (int q=0;q<16;q++){ float4 v = xr[q]; x[4*q]=v.x; x[4*q+1]=v.y; x[4*q+2]=v.z; x[4*q+3]=v.w; }
  float* orow = out + n*64;
  for (int j=0;j<DIM;j++){
    const float* wr = w1 + j*DIM;   // uniform -> s_load
    float t = 0.f;
    #pragma unroll
    for (int k=0;k<DIM;k++) t += x[k]*wr[k];
    orow[j] = t;
  }
}

// node[n] += sp(agg[n]@nl2.T + nl2_b) @ nl3.T + nl3_b
__global__ __launch_bounds__(64) void node_update_kernel(float* __restrict__ node,
                                                         const float* __restrict__ agg,
                                                         const float* __restrict__ nl2_w,
                                                         const float* __restrict__ nl2_b,
                                                         const float* __restrict__ nl3t,
                                                         const float* __restrict__ nl3_b,
                                                         int N){
  int lane = threadIdx.x;
  long n = (long)blockIdx.x*64 + lane;
  if (n >= N) return;
  float x[DIM];
  const float4* ar = (const float4*)(agg + n*64);
  #pragma unroll
  for (int q=0;q<16;q++){ float4 v = ar[q]; x[4*q]=v.x; x[4*q+1]=v.y; x[4*q+2]=v.z; x[4*q+3]=v.w; }
  float acc[DIM];
  #pragma unroll
  for (int j=0;j<DIM;j++) acc[j] = 0.f;
  for (int k=0;k<DIM;k++){
    float t = nl2_b[k];
    const float* wr = nl2_w + k*DIM;      // uniform row -> s_load
    #pragma unroll
    for (int m=0;m<DIM;m++) t += x[m]*wr[m];
    float s = sp_f(t);
    const float* w3 = nl3t + k*DIM;       // k-major transposed
    #pragma unroll
    for (int j=0;j<DIM;j++) acc[j] += s*w3[j];
  }
  float4* nr = (float4*)(node + n*64);
  #pragma unroll
  for (int q=0;q<16;q++){
    float4 v = nr[q];
    v.x += acc[4*q]   + nl3_b[4*q];
    v.y += acc[4*q+1] + nl3_b[4*q+1];
    v.z += acc[4*q+2] + nl3_b[4*q+2];
    v.w += acc[4*q+3] + nl3_b[4*q+3];
    nr[q] = v;
  }
}

// ---------------- fused edge kernel ----------------

__global__ __launch_bounds__(64) void edge_kernel(const float* __restrict__ dist,
                                                  const int* __restrict__ src,
                                                  const int* __restrict__ dst,
                                                  const unsigned char* __restrict__ flag,
                                                  const float* __restrict__ edge_mask,
                                                  const float* __restrict__ cf_w1,  // [64][50]
                                                  const float* __restrict__ cf_b1,  // [64]
                                                  const float* __restrict__ w2t,    // [64][64] k-major
                                                  const float* __restrict__ cf_b2,  // [64]
                                                  const float* __restrict__ new_node,
                                                  float* __restrict__ agg,
                                                  int E){
  __shared__ float hb[64*65];
  int lane = threadIdx.x;
  int e0 = blockIdx.x*64;
  int e = e0 + lane;
  int ee = e < E ? e : 0;
  float d = dist[ee];
  bool msel = flag[ee] != 0;

  // RBF features (per lane = per edge), centers folded at compile time in double
  float rbf[NC];
  #pragma unroll
  for (int m=0;m<NC;m++){
    float c = (m == NC-1) ? 5.0f : (float)((double)m * (5.0 / 49.0));
    float df = d - c;
    float r = __expf((float)(-1.0/(5.0/49.0)) * df * df);
    rbf[m] = msel ? edge_mask[m] : r;
  }

  float h[DIM];
  #pragma unroll
  for (int j=0;j<DIM;j++) h[j] = cf_b2[j];

  for (int k=0;k<DIM;k++){
    float t = cf_b1[k];
    const float* w1r = cf_w1 + k*NC;    // uniform -> s_load
    #pragma unroll
    for (int m=0;m<NC;m++) t += rbf[m]*w1r[m];
    float spt = sp_f(t);
    const float* w2r = w2t + k*DIM;     // uniform -> s_load
    #pragma unroll
    for (int j=0;j<DIM;j++) h[j] += spt*w2r[j];
  }

  // stage h into LDS (padded) for a coalesced gather/scatter phase
  #pragma unroll
  for (int j=0;j<DIM;j++) hb[lane*65 + j] = h[j];
  __syncthreads();

  int nvalid = E - e0; if (nvalid > 64) nvalid = 64;
  for (int q=0;q<nvalid;q++){
    int s  = src[e0 + q];     // uniform -> s_load
    int dn = dst[e0 + q];     // uniform -> s_load
    float nn = new_node[(long)s*64 + lane];      // 256B coalesced
    float m  = nn * hb[q*65 + lane];
    unsafeAtomicAdd(&agg[(long)dn*64 + lane], m); // 256B coalesced hw f32 atomic
  }
}

// ---------------- heads ----------------

__global__ __launch_bounds__(64) void node_head_kernel(const float* __restrict__ node,
                                                       const int* __restrict__ nidx,
                                                       const float* __restrict__ nt1_w,
                                                       const float* __restrict__ nt1_b,
                                                       const float* __restrict__ nt2_w,
                                                       const float* __restrict__ nt2_b,
                                                       float* __restrict__ out, int NSEL){
  int lane = threadIdx.x;
  int r = blockIdx.x*64 + lane;
  if (r >= NSEL) return;
  long n = nidx[r];
  float x[DIM];
  const float4* xr = (const float4*)(node + n*64);
  #pragma unroll
  for (int q=0;q<16;q++){ float4 v = xr[q]; x[4*q]=v.x; x[4*q+1]=v.y; x[4*q+2]=v.z; x[4*q+3]=v.w; }
  float o0 = nt2_b[0], o1 = nt2_b[1], o2 = nt2_b[2];
  for (int j=0;j<32;j++){
    float t = nt1_b[j];
    const float* w = nt1_w + j*DIM;     // uniform
    #pragma unroll
    for (int k=0;k<DIM;k++) t += x[k]*w[k];
    o0 += t*nt2_w[j];
    o1 += t*nt2_w[32+j];
    o2 += t*nt2_w[64+j];
  }
  out[(long)r*3+0]=o0; out[(long)r*3+1]=o1; out[(long)r*3+2]=o2;
}

__global__ __launch_bounds__(64) void edge_head_kernel(const float* __restrict__ node,
                                                       const int* __restrict__ sidx,
                                                       const int* __restrict__ tidx,
                                                       const float* __restrict__ et1t, // [128][64] k-major
                                                       const float* __restrict__ et1_b,
                                                       const float* __restrict__ et2_w, // [5][64]
                                                       const float* __restrict__ et2_b,
                                                       float* __restrict__ out, int ESEL){
  int lane = threadIdx.x;
  int r = blockIdx.x*64 + lane;
  if (r >= ESEL) return;
  long s = sidx[r], t2 = tidx[r];
  float acc[DIM];
  #pragma unroll
  for (int j=0;j<DIM;j++) acc[j] = 0.f;
  for (int k=0;k<DIM;k++){
    float xk = node[s*64 + k];
    const float* w = et1t + k*DIM;
    #pragma unroll
    for (int j=0;j<DIM;j++) acc[j] += xk*w[j];
  }
  for (int k=0;k<DIM;k++){
    float xk = node[t2*64 + k];
    const float* w = et1t + (64+k)*DIM;
    #pragma unroll
    for (int j=0;j<DIM;j++) acc[j] += xk*w[j];
  }
  #pragma unroll
  for (int j=0;j<DIM;j++) acc[j] += et1_b[j];
  #pragma unroll
  for (int q=0;q<5;q++){
    float t = et2_b[q];
    const float* w = et2_w + q*DIM;
    #pragma unroll
    for (int k=0;k<DIM;k++) t += acc[k]*w[k];
    out[(long)r*5 + q] = t;
  }
}

// ---------------- launch ----------------

extern "C" void kernel_launch(void* const* d_in, const int* in_sizes, int n_in,
                              void* d_out, int out_size, void* d_ws, size_t ws_size,
                              hipStream_t stream){
  const float* emb      = (const float*)d_in[0];
  const float* dist     = (const float*)d_in[1];
  const float* edge_mask= (const float*)d_in[2];
  const float* conv_w1  = (const float*)d_in[3];
  const float* cf_w1    = (const float*)d_in[4];
  const float* cf_b1    = (const float*)d_in[5];
  const float* cf_w2    = (const float*)d_in[6];
  const float* cf_b2    = (const float*)d_in[7];
  const float* nl2_w    = (const float*)d_in[8];
  const float* nl2_b    = (const float*)d_in[9];
  const float* nl3_w    = (const float*)d_in[10];
  const float* nl3_b    = (const float*)d_in[11];
  const float* nt1_w    = (const float*)d_in[12];
  const float* nt1_b    = (const float*)d_in[13];
  const float* nt2_w    = (const float*)d_in[14];
  const float* nt2_b    = (const float*)d_in[15];
  const float* et1_w    = (const float*)d_in[16];
  const float* et1_b    = (const float*)d_in[17];
  const float* et2_w    = (const float*)d_in[18];
  const float* et2_b    = (const float*)d_in[19];
  const int* node_type  = (const int*)d_in[20];
  const int* src        = (const int*)d_in[21];
  const int* dst        = (const int*)d_in[22];
  const int* sel        = (const int*)d_in[23];
  const int* node_index = (const int*)d_in[24];
  const int* source_index = (const int*)d_in[25];
  const int* target_index = (const int*)d_in[26];

  int E    = in_sizes[1];
  int N    = in_sizes[20];
  int K    = in_sizes[23];
  int NSEL = in_sizes[24];
  int ESEL = in_sizes[25];

  size_t N64 = (size_t)N*64;
  float* node     = (float*)d_ws;
  float* new_node = node + N64;
  float* agg      = new_node + N64;
  float* w2t      = agg + N64;
  float* nl3t     = w2t + 3*4096;
  float* et1t     = nl3t + 3*4096;
  unsigned char* flag = (unsigned char*)(et1t + 128*64);

  flag_zero_kernel<<<(E+255)/256, 256, 0, stream>>>(flag, E);
  flag_set_kernel<<<(K+255)/256, 256, 0, stream>>>(sel, flag, K);
  prep_transpose_kernel<<<48, 256, 0, stream>>>(cf_w2, nl3_w, et1_w, w2t, nl3t, et1t);
  node_init_kernel<<<(int)((N64+255)/256), 256, 0, stream>>>(emb, node_type, node, N);

  int nb_node = (N+63)/64, nb_edge = (E+63)/64;
  for (int i=0;i<3;i++){
    new_node_kernel<<<nb_node, 64, 0, stream>>>(node, conv_w1 + i*4096, new_node, N);
    hipMemsetAsync(agg, 0, N64*sizeof(float), stream);
    edge_kernel<<<nb_edge, 64, 0, stream>>>(dist, src, dst, flag, edge_mask,
        cf_w1 + i*64*50, cf_b1 + i*64, w2t + i*4096, cf_b2 + i*64,
        new_node, agg, E);
    node_update_kernel<<<nb_node, 64, 0, stream>>>(node, agg, nl2_w + i*4096, nl2_b + i*64,
        nl3t + i*4096, nl3_b + i*64, N);
  }

  node_head_kernel<<<(NSEL+63)/64, 64, 0, stream>>>(node, node_index,
      nt1_w, nt1_b, nt2_w, nt2_b, (float*)d_out, NSEL);
  edge_head_kernel<<<(ESEL+63)/64, 64, 0, stream>>>(node, source_index, target_index,
      et1t, et1_b, et2_w, et2_b, (float*)d_out + (size_t)NSEL*3, ESEL);
}

// Round 3
// 847.491 us; speedup vs baseline: 3.8643x; 3.8643x over previous
//
#include <hip/hip_runtime.h>

#define DIM 64
#define NC 50
#define TABN 2048
#define TABP (TABN + 2)   // rows 0..2047 = interp pairs, 2048 = pad, 2049 = mask row

__device__ __forceinline__ float sp_f(float x){
  // torch Softplus(beta=0.5, threshold=14): 2*log(1+exp(0.5x)), linear when 0.5x>14
  float e = __expf(0.5f*x);
  float s = 2.0f*__logf(1.0f+e);
  return x > 28.0f ? x : s;
}

// ---------------- prep kernels ----------------

__global__ void flag_zero_kernel(unsigned char* flag, int E){
  int id = blockIdx.x*256 + threadIdx.x;
  if (id < E) flag[id] = 0;
}

__global__ void flag_set_kernel(const int* __restrict__ sel, unsigned char* flag, int K){
  int id = blockIdx.x*256 + threadIdx.x;
  if (id < K) flag[sel[id]] = 1;
}

// transposes: all [j][k] -> [k][j] (k-major) so lane=j reads are coalesced
__global__ void prep_transpose_kernel(const float* __restrict__ cf_w2,
                                      const float* __restrict__ nl3_w,
                                      const float* __restrict__ conv_w1,
                                      const float* __restrict__ nl2_w,
                                      const float* __restrict__ et1_w,
                                      const float* __restrict__ nt1_w,
                                      float* __restrict__ w2t,
                                      float* __restrict__ nl3t,
                                      float* __restrict__ cw1t,
                                      float* __restrict__ nl2t,
                                      float* __restrict__ et1t,
                                      float* __restrict__ nt1t){
  int id = blockIdx.x*256 + threadIdx.x;
  if (id < 3*4096){
    int i = id >> 12, r = id & 4095;
    int k = r >> 6, j = r & 63;
    int s = i*4096 + j*64 + k;
    w2t[id]  = cf_w2[s];
    nl3t[id] = nl3_w[s];
    cw1t[id] = conv_w1[s];
    nl2t[id] = nl2_w[s];
  }
  if (id < 128*64){
    int k = id >> 6, j = id & 63;
    et1t[id] = et1_w[j*128 + k];   // et1_w is [64][128]
  }
  if (id < 64*32){
    int k = id >> 5, j = id & 31;
    nt1t[id] = nt1_w[j*64 + k];    // nt1_w is [32][64]
  }
}

__global__ void node_init_kernel(const float* __restrict__ emb,
                                 const int* __restrict__ node_type,
                                 float* __restrict__ node, int N){
  long id = (long)blockIdx.x*256 + threadIdx.x;
  if (id < (long)N*64){
    int n = (int)(id >> 6), j = (int)(id & 63);
    node[id] = emb[(long)node_type[n]*64 + j];
  }
}

// ---------------- CSR build ----------------

__global__ void hist_kernel(const int* __restrict__ dst, int* __restrict__ counts, int E){
  int e = blockIdx.x*256 + threadIdx.x;
  if (e < E) atomicAdd(&counts[dst[e]], 1);
}

// single-block exclusive scan of counts[0..N-1] -> offs[0..N]
__global__ __launch_bounds__(1024) void scan_kernel(const int* __restrict__ counts,
                                                    int* __restrict__ offs, int N){
  __shared__ int part[1024];
  int t = threadIdx.x;
  int chunk = (N + 1023) / 1024;
  int b = t*chunk, e = b + chunk; if (e > N) e = N;
  int s = 0;
  for (int i=b;i<e;i++) s += counts[i];
  part[t] = s;
  __syncthreads();
  for (int off=1; off<1024; off<<=1){
    int v = (t >= off) ? part[t-off] : 0;
    __syncthreads();
    part[t] += v;
    __syncthreads();
  }
  int base = (t == 0) ? 0 : part[t-1];
  for (int i=b;i<e;i++){ offs[i] = base; base += counts[i]; }
  if (t == 1023) offs[N] = part[1023];
}

__global__ void cursor_init_kernel(const int* __restrict__ offs, int* __restrict__ cursor, int N){
  int id = blockIdx.x*256 + threadIdx.x;
  if (id < N) cursor[id] = offs[id];
}

// dst-sorted edge stream: csr_t = table coordinate (or mask row), csr_src = src node
__global__ void scatter_kernel(const float* __restrict__ dist,
                               const int* __restrict__ src,
                               const int* __restrict__ dst,
                               const unsigned char* __restrict__ flag,
                               int* __restrict__ cursor,
                               float* __restrict__ csr_t,
                               int* __restrict__ csr_src, int E){
  int e = blockIdx.x*256 + threadIdx.x;
  if (e >= E) return;
  int dn = dst[e];
  int pos = atomicAdd(&cursor[dn], 1);
  float d = dist[e];
  float t = flag[e] ? (float)(TABN+1)
                    : fminf(d * ((float)TABN/5.0f), (float)TABN - 0.001f);
  csr_t[pos]   = t;
  csr_src[pos] = src[e];
}

// ---------------- filter table build ----------------
// h(d) = sp(rbf(d)@W1^T + b1)@W2^T + b2 is a smooth fn of scalar d -> tabulate.
// tab2[l][i][j] = (h_i[j], h_{i+1}[j]) so one float2 load gives both lerp endpoints.

__global__ __launch_bounds__(64) void table_kernel(const float* __restrict__ edge_mask,
                                                   const float* __restrict__ cf_w1,
                                                   const float* __restrict__ cf_b1,
                                                   const float* __restrict__ w2t,
                                                   const float* __restrict__ cf_b2,
                                                   float* __restrict__ tab2){
  int l = blockIdx.y;
  int p = blockIdx.x*64 + threadIdx.x;
  if (p >= TABP) return;
  float rbf[NC];
  if (p == TABN+1){
    #pragma unroll
    for (int m=0;m<NC;m++) rbf[m] = edge_mask[m];
  } else {
    float d = (float)p * (5.0f/(float)TABN);   // 5/2048 exact in f32
    #pragma unroll
    for (int m=0;m<NC;m++){
      float c = (m == NC-1) ? 5.0f : (float)((double)m * (5.0/49.0));
      float df = d - c;
      rbf[m] = __expf((float)(-1.0/(5.0/49.0)) * df * df);
    }
  }
  const float* W1 = cf_w1 + l*DIM*NC;
  const float* B1 = cf_b1 + l*DIM;
  const float* W2 = w2t  + l*DIM*DIM;
  const float* B2 = cf_b2 + l*DIM;
  float h[DIM];
  #pragma unroll
  for (int j=0;j<DIM;j++) h[j] = B2[j];
  for (int k=0;k<DIM;k++){
    float t = B1[k];
    const float* w1r = W1 + k*NC;
    #pragma unroll
    for (int m=0;m<NC;m++) t += rbf[m]*w1r[m];
    float spt = sp_f(t);
    const float* w2r = W2 + k*DIM;
    #pragma unroll
    for (int j=0;j<DIM;j++) h[j] += spt*w2r[j];
  }
  float* T = tab2 + ((size_t)l*TABP + p)*2*DIM;
  #pragma unroll
  for (int j=0;j<DIM;j++) T[2*j] = h[j];           // .x of row p
  if (p >= 1){
    float* Tp = T - 2*DIM;
    #pragma unroll
    for (int j=0;j<DIM;j++) Tp[2*j+1] = h[j];      // .y of row p-1
  }
  if (p == TABN+1){
    #pragma unroll
    for (int j=0;j<DIM;j++) T[2*j+1] = h[j];       // mask row: (hm, hm), frac=0
  }
}

// ---------------- per-layer kernels (wave=node, lane=feature) ----------------

__global__ __launch_bounds__(256) void new_node_kernel(const float* __restrict__ node,
                                                       const float* __restrict__ cw1t,
                                                       float* __restrict__ out, int N){
  int n = __builtin_amdgcn_readfirstlane(blockIdx.x*4 + (threadIdx.x>>6));
  int lane = threadIdx.x & 63;
  if (n >= N) return;
  const float* x = node + (long)n*64;          // wave-uniform row -> s_loads
  float acc = 0.f;
  #pragma unroll
  for (int k=0;k<DIM;k++) acc += x[k]*cw1t[k*64 + lane];   // coalesced, L1-hot
  out[(long)n*64 + lane] = acc;
}

// gather-aggregate: wave owns 2 dst nodes, lane=feature; no atomics, no LDS
__global__ __launch_bounds__(256) void agg_kernel(const float* __restrict__ csr_t,
                                                  const int* __restrict__ csr_src,
                                                  const int* __restrict__ offs,
                                                  const float2* __restrict__ tab2,
                                                  const float* __restrict__ new_node,
                                                  float* __restrict__ agg, int N){
  int w = __builtin_amdgcn_readfirstlane(blockIdx.x*4 + (threadIdx.x>>6));
  int lane = threadIdx.x & 63;
  int n0 = w*2;
  for (int n=n0; n<n0+2 && n<N; ++n){
    int beg = offs[n], end = offs[n+1];
    float acc0 = 0.f, acc1 = 0.f;
    int i = beg;
    for (; i+2 <= end; i += 2){
      float t0 = csr_t[i], t1 = csr_t[i+1];        // uniform -> s_load
      int   s0 = csr_src[i], s1 = csr_src[i+1];
      float f0 = floorf(t0), f1 = floorf(t1);
      float2 ab0 = tab2[((int)f0)*64 + lane];      // 512B from L2-hot table
      float2 ab1 = tab2[((int)f1)*64 + lane];
      float nn0 = new_node[(long)s0*64 + lane];    // 256B coalesced random row
      float nn1 = new_node[(long)s1*64 + lane];
      acc0 += nn0 * (ab0.x + (t0-f0)*(ab0.y-ab0.x));
      acc1 += nn1 * (ab1.x + (t1-f1)*(ab1.y-ab1.x));
    }
    if (i < end){
      float t0 = csr_t[i]; int s0 = csr_src[i];
      float f0 = floorf(t0);
      float2 ab0 = tab2[((int)f0)*64 + lane];
      float nn0 = new_node[(long)s0*64 + lane];
      acc0 += nn0 * (ab0.x + (t0-f0)*(ab0.y-ab0.x));
    }
    agg[(long)n*64 + lane] = acc0 + acc1;          // plain coalesced store
  }
}

__global__ __launch_bounds__(256) void node_update_kernel(float* __restrict__ node,
                                                          const float* __restrict__ agg,
                                                          const float* __restrict__ nl2t,
                                                          const float* __restrict__ nl2_b,
                                                          const float* __restrict__ nl3t,
                                                          const float* __restrict__ nl3_b,
                                                          int N){
  int n = __builtin_amdgcn_readfirstlane(blockIdx.x*4 + (threadIdx.x>>6));
  int lane = threadIdx.x & 63;
  if (n >= N) return;
  const float* a = agg + (long)n*64;               // wave-uniform -> s_loads
  float u = nl2_b[lane];
  #pragma unroll
  for (int m=0;m<DIM;m++) u += a[m]*nl2t[m*64 + lane];
  float spu = sp_f(u);
  float acc = nl3_b[lane];
  #pragma unroll
  for (int k=0;k<DIM;k++) acc += __shfl(spu, k)*nl3t[k*64 + lane];
  node[(long)n*64 + lane] += acc;
}

// ---------------- heads (wave=row, lane=feature) ----------------

__global__ __launch_bounds__(256) void node_head_kernel(const float* __restrict__ node,
                                                        const int* __restrict__ nidx,
                                                        const float* __restrict__ nt1t,  // [64][32]
                                                        const float* __restrict__ nt1_b,
                                                        const float* __restrict__ nt2_w, // [3][32]
                                                        const float* __restrict__ nt2_b,
                                                        float* __restrict__ out, int NSEL){
  int r = __builtin_amdgcn_readfirstlane(blockIdx.x*4 + (threadIdx.x>>6));
  int lane = threadIdx.x & 63;
  if (r >= NSEL) return;
  long n = nidx[r];
  const float* x = node + n*64;                    // uniform -> s_loads
  float u = 0.f;
  if (lane < 32){
    u = nt1_b[lane];
    #pragma unroll
    for (int k=0;k<DIM;k++) u += x[k]*nt1t[k*32 + lane];
  }
  #pragma unroll
  for (int q=0;q<3;q++){
    float v = (lane < 32) ? u*nt2_w[q*32 + lane] : 0.f;
    #pragma unroll
    for (int o=32;o>=1;o>>=1) v += __shfl_xor(v, o);
    if (lane == 0) out[(long)r*3 + q] = nt2_b[q] + v;
  }
}

__global__ __launch_bounds__(256) void edge_head_kernel(const float* __restrict__ node,
                                                        const int* __restrict__ sidx,
                                                        const int* __restrict__ tidx,
                                                        const float* __restrict__ et1t, // [128][64]
                                                        const float* __restrict__ et1_b,
                                                        const float* __restrict__ et2_w,// [5][64]
                                                        const float* __restrict__ et2_b,
                                                        float* __restrict__ out, int ESEL){
  int r = __builtin_amdgcn_readfirstlane(blockIdx.x*4 + (threadIdx.x>>6));
  int lane = threadIdx.x & 63;
  if (r >= ESEL) return;
  long s = sidx[r], t = tidx[r];
  const float* xs = node + s*64;                   // uniform -> s_loads
  const float* xt = node + t*64;
  float acc = et1_b[lane];
  #pragma unroll
  for (int k=0;k<DIM;k++) acc += xs[k]*et1t[k*64 + lane];
  #pragma unroll
  for (int k=0;k<DIM;k++) acc += xt[k]*et1t[(64+k)*64 + lane];
  #pragma unroll
  for (int q=0;q<5;q++){
    float v = acc * et2_w[q*64 + lane];
    #pragma unroll
    for (int o=32;o>=1;o>>=1) v += __shfl_xor(v, o);
    if (lane == 0) out[(long)r*5 + q] = et2_b[q] + v;
  }
}

// ---------------- launch ----------------

extern "C" void kernel_launch(void* const* d_in, const int* in_sizes, int n_in,
                              void* d_out, int out_size, void* d_ws, size_t ws_size,
                              hipStream_t stream){
  const float* emb      = (const float*)d_in[0];
  const float* dist     = (const float*)d_in[1];
  const float* edge_mask= (const float*)d_in[2];
  const float* conv_w1  = (const float*)d_in[3];
  const float* cf_w1    = (const float*)d_in[4];
  const float* cf_b1    = (const float*)d_in[5];
  const float* cf_w2    = (const float*)d_in[6];
  const float* cf_b2    = (const float*)d_in[7];
  const float* nl2_w    = (const float*)d_in[8];
  const float* nl2_b    = (const float*)d_in[9];
  const float* nl3_w    = (const float*)d_in[10];
  const float* nl3_b    = (const float*)d_in[11];
  const float* nt1_w    = (const float*)d_in[12];
  const float* nt1_b    = (const float*)d_in[13];
  const float* nt2_w    = (const float*)d_in[14];
  const float* nt2_b    = (const float*)d_in[15];
  const float* et1_w    = (const float*)d_in[16];
  const float* et1_b    = (const float*)d_in[17];
  const float* et2_w    = (const float*)d_in[18];
  const float* et2_b    = (const float*)d_in[19];
  const int* node_type  = (const int*)d_in[20];
  const int* src        = (const int*)d_in[21];
  const int* dst        = (const int*)d_in[22];
  const int* sel        = (const int*)d_in[23];
  const int* node_index = (const int*)d_in[24];
  const int* source_index = (const int*)d_in[25];
  const int* target_index = (const int*)d_in[26];

  int E    = in_sizes[1];
  int N    = in_sizes[20];
  int K    = in_sizes[23];
  int NSEL = in_sizes[24];
  int ESEL = in_sizes[25];

  size_t N64 = (size_t)N*64;
  float* p = (float*)d_ws;
  float* node     = p; p += N64;
  float* new_node = p; p += N64;
  float* agg      = p; p += N64;
  float* cw1t     = p; p += 3*4096;
  float* w2t      = p; p += 3*4096;
  float* nl2t     = p; p += 3*4096;
  float* nl3t     = p; p += 3*4096;
  float* et1t     = p; p += 128*64;
  float* nt1t     = p; p += 64*32;
  float* tab2     = p; p += (size_t)3*TABP*2*DIM;
  float* csr_t    = p; p += E;
  int*   csr_src  = (int*)p; p += E;
  int*   counts   = (int*)p; p += (N+1);
  int*   offs     = (int*)p; p += (N+1);
  int*   cursor   = (int*)p; p += N;
  unsigned char* flag = (unsigned char*)p;

  // masked-edge flags
  flag_zero_kernel<<<(E+255)/256, 256, 0, stream>>>(flag, E);
  flag_set_kernel<<<(K+255)/256, 256, 0, stream>>>(sel, flag, K);
  // weight transposes
  prep_transpose_kernel<<<48, 256, 0, stream>>>(cf_w2, nl3_w, conv_w1, nl2_w, et1_w, nt1_w,
                                                w2t, nl3t, cw1t, nl2t, et1t, nt1t);
  // node embedding init
  node_init_kernel<<<(int)((N64+255)/256), 256, 0, stream>>>(emb, node_type, node, N);
  // CSR by dst
  hipMemsetAsync(counts, 0, (size_t)(N+1)*sizeof(int), stream);
  hist_kernel<<<(E+255)/256, 256, 0, stream>>>(dst, counts, E);
  scan_kernel<<<1, 1024, 0, stream>>>(counts, offs, N);
  cursor_init_kernel<<<(N+255)/256, 256, 0, stream>>>(offs, cursor, N);
  scatter_kernel<<<(E+255)/256, 256, 0, stream>>>(dist, src, dst, flag, cursor, csr_t, csr_src, E);
  // filter tables (3 layers)
  dim3 tg((TABP+63)/64, 3);
  table_kernel<<<tg, 64, 0, stream>>>(edge_mask, cf_w1, cf_b1, w2t, cf_b2, tab2);

  int nb_node = (N+3)/4;
  int nb_agg  = (N+7)/8;
  for (int l=0;l<3;l++){
    new_node_kernel<<<nb_node, 256, 0, stream>>>(node, cw1t + l*4096, new_node, N);
    agg_kernel<<<nb_agg, 256, 0, stream>>>(csr_t, csr_src, offs,
        (const float2*)(tab2 + (size_t)l*TABP*2*DIM), new_node, agg, N);
    node_update_kernel<<<nb_node, 256, 0, stream>>>(node, agg, nl2t + l*4096, nl2_b + l*64,
        nl3t + l*4096, nl3_b + l*64, N);
  }

  node_head_kernel<<<(NSEL+3)/4, 256, 0, stream>>>(node, node_index,
      nt1t, nt1_b, nt2_w, nt2_b, (float*)d_out, NSEL);
  edge_head_kernel<<<(ESEL+3)/4, 256, 0, stream>>>(node, source_index, target_index,
      et1t, et1_b, et2_w, et2_b, (float*)d_out + (size_t)NSEL*3, ESEL);
}

// Round 4
// 710.975 us; speedup vs baseline: 4.6062x; 1.1920x over previous
//
#include <hip/hip_runtime.h>

#define DIM 64
#define NC 50
#define TABN 2048
#define TABP (TABN + 2)   // rows 0..2047 = interp pairs, 2048 = pad, 2049 = mask row

__device__ __forceinline__ float sp_f(float x){
  // torch Softplus(beta=0.5, threshold=14): 2*log(1+exp(0.5x)), linear when 0.5*x>14
  float e = __expf(0.5f*x);
  float s = 2.0f*__logf(1.0f+e);
  return x > 28.0f ? x : s;
}

__device__ __forceinline__ float rdl(float v, int l){
  return __int_as_float(__builtin_amdgcn_readlane(__float_as_int(v), l));
}

// ---------------- prep kernels ----------------

// fused: zero flag + histogram dst
__global__ void hist_flag_kernel(const int* __restrict__ dst, unsigned char* __restrict__ flag,
                                 int* __restrict__ counts, int E){
  int e = blockIdx.x*256 + threadIdx.x;
  if (e < E){ flag[e] = 0; atomicAdd(&counts[dst[e]], 1); }
}

__global__ void flag_set_kernel(const int* __restrict__ sel, unsigned char* flag, int K){
  int id = blockIdx.x*256 + threadIdx.x;
  if (id < K) flag[sel[id]] = 1;
}

// transposes: all [j][k] -> [k][j] (k-major) so lane=j reads are coalesced
__global__ void prep_transpose_kernel(const float* __restrict__ cf_w2,
                                      const float* __restrict__ nl3_w,
                                      const float* __restrict__ conv_w1,
                                      const float* __restrict__ nl2_w,
                                      const float* __restrict__ et1_w,
                                      const float* __restrict__ nt1_w,
                                      float* __restrict__ w2t,
                                      float* __restrict__ nl3t,
                                      float* __restrict__ cw1t,
                                      float* __restrict__ nl2t,
                                      float* __restrict__ et1t,
                                      float* __restrict__ nt1t){
  int id = blockIdx.x*256 + threadIdx.x;
  if (id < 3*4096){
    int i = id >> 12, r = id & 4095;
    int k = r >> 6, j = r & 63;
    int s = i*4096 + j*64 + k;
    w2t[id]  = cf_w2[s];
    nl3t[id] = nl3_w[s];
    cw1t[id] = conv_w1[s];
    nl2t[id] = nl2_w[s];
  }
  if (id < 128*64){
    int k = id >> 6, j = id & 63;
    et1t[id] = et1_w[j*128 + k];   // et1_w is [64][128]
  }
  if (id < 64*32){
    int k = id >> 5, j = id & 31;
    nt1t[id] = nt1_w[j*64 + k];    // nt1_w is [32][64]
  }
}

// ---------------- scan (single block, coalesced tiles, shfl-based) ----------------

__global__ __launch_bounds__(1024) void scan_kernel(const int* __restrict__ counts,
                                                    int* __restrict__ offs,
                                                    int* __restrict__ cursor, int N){
  __shared__ int wexcl[16];
  __shared__ int s_tt;
  __shared__ int s_carry;
  int t = threadIdx.x, lane = t & 63, wid = t >> 6;
  if (t == 0) s_carry = 0;
  for (int base = 0; base < N; base += 1024){
    int i = base + t;
    int v = (i < N) ? counts[i] : 0;
    int x = v;
    #pragma unroll
    for (int off=1; off<64; off<<=1){ int u = __shfl_up(x, off); if (lane >= off) x += u; }
    __syncthreads();                     // previous tile fully consumed wexcl/s_carry
    if (lane == 63) wexcl[wid] = x;
    __syncthreads();
    if (wid == 0 && lane < 16){
      int orig = wexcl[lane];
      int s = orig;
      #pragma unroll
      for (int off=1; off<16; off<<=1){ int u = __shfl_up(s, off); if (lane >= off) s += u; }
      wexcl[lane] = s - orig;            // exclusive wave base
      if (lane == 15) s_tt = s;          // tile total
    }
    __syncthreads();
    int excl = s_carry + wexcl[wid] + (x - v);
    if (i < N){ offs[i] = excl; cursor[i] = excl; }
    __syncthreads();
    if (t == 0) s_carry += s_tt;
  }
  __syncthreads();
  if (t == 0) offs[N] = s_carry;
}

// dst-sorted edge stream, packed: float2{frac, bitcast((src<<12)|tab_idx)}
__global__ void scatter_kernel(const float* __restrict__ dist,
                               const int* __restrict__ src,
                               const int* __restrict__ dst,
                               const unsigned char* __restrict__ flag,
                               int* __restrict__ cursor,
                               float2* __restrict__ csr, int E){
  int e = blockIdx.x*256 + threadIdx.x;
  if (e >= E) return;
  int dn = dst[e];
  int pos = atomicAdd(&cursor[dn], 1);
  float d = dist[e];
  int idx; float fr;
  if (flag[e]){ idx = TABN + 1; fr = 0.f; }
  else {
    float tf = fminf(d * ((float)TABN/5.0f), (float)TABN - 0.001f);
    idx = (int)tf;
    fr = tf - (float)idx;
  }
  int packed = (src[e] << 12) | idx;     // src < 2^19, idx < 4096
  csr[pos] = make_float2(fr, __int_as_float(packed));
}

// ---------------- filter table build ----------------
// h(d) = sp(rbf(d)@W1^T + b1)@W2^T + b2 is a smooth fn of scalar d -> tabulate.
// tab2[l][i][j] = (h_i[j], h_{i+1}[j]) so one float2 load gives both lerp endpoints.

__global__ __launch_bounds__(64) void table_kernel(const float* __restrict__ edge_mask,
                                                   const float* __restrict__ cf_w1,
                                                   const float* __restrict__ cf_b1,
                                                   const float* __restrict__ w2t,
                                                   const float* __restrict__ cf_b2,
                                                   float* __restrict__ tab2){
  int l = blockIdx.y;
  int p = blockIdx.x*64 + threadIdx.x;
  if (p >= TABP) return;
  float rbf[NC];
  if (p == TABN+1){
    #pragma unroll
    for (int m=0;m<NC;m++) rbf[m] = edge_mask[m];
  } else {
    float d = (float)p * (5.0f/(float)TABN);
    #pragma unroll
    for (int m=0;m<NC;m++){
      float c = (m == NC-1) ? 5.0f : (float)((double)m * (5.0/49.0));
      float df = d - c;
      rbf[m] = __expf((float)(-1.0/(5.0/49.0)) * df * df);
    }
  }
  const float* W1 = cf_w1 + l*DIM*NC;
  const float* B1 = cf_b1 + l*DIM;
  const float* W2 = w2t  + l*DIM*DIM;
  const float* B2 = cf_b2 + l*DIM;
  float h[DIM];
  #pragma unroll
  for (int j=0;j<DIM;j++) h[j] = B2[j];
  for (int k=0;k<DIM;k++){
    float t = B1[k];
    const float* w1r = W1 + k*NC;
    #pragma unroll
    for (int m=0;m<NC;m++) t += rbf[m]*w1r[m];
    float spt = sp_f(t);
    const float* w2r = W2 + k*DIM;
    #pragma unroll
    for (int j=0;j<DIM;j++) h[j] += spt*w2r[j];
  }
  float* T = tab2 + ((size_t)l*TABP + p)*2*DIM;
  #pragma unroll
  for (int j=0;j<DIM;j++) T[2*j] = h[j];           // .x of row p
  if (p >= 1){
    float* Tp = T - 2*DIM;
    #pragma unroll
    for (int j=0;j<DIM;j++) Tp[2*j+1] = h[j];      // .y of row p-1
  }
  if (p == TABN+1){
    #pragma unroll
    for (int j=0;j<DIM;j++) T[2*j+1] = h[j];       // mask row: (hm, hm), frac=0
  }
}

// ---------------- node-side kernels (wave = 4 nodes, lane = feature) ----------------

// node = emb[node_type]; new_node = node @ W1[0]^T
__global__ __launch_bounds__(256) void node_init_nn_kernel(const float* __restrict__ emb,
                                                           const int* __restrict__ node_type,
                                                           const float* __restrict__ cw1t,
                                                           float* __restrict__ node,
                                                           float* __restrict__ new_node, int N){
  int wid = threadIdx.x >> 6, lane = threadIdx.x & 63;
  int n0 = (blockIdx.x*4 + wid)*4;
  if (n0 >= N) return;
  float nv[4], o[4];
  #pragma unroll
  for (int i=0;i<4;i++){
    int n = n0+i < N ? n0+i : N-1;
    nv[i] = emb[(long)node_type[n]*64 + lane];
    o[i] = 0.f;
  }
  #pragma unroll 16
  for (int k=0;k<DIM;k++){
    float w = cw1t[k*64 + lane];
    #pragma unroll
    for (int i=0;i<4;i++) o[i] = fmaf(rdl(nv[i], k), w, o[i]);
  }
  #pragma unroll
  for (int i=0;i<4;i++){
    if (n0+i < N){
      node[(long)(n0+i)*64 + lane] = nv[i];
      new_node[(long)(n0+i)*64 + lane] = o[i];
    }
  }
}

// gather-aggregate: wave = 1 dst node, lane = feature; csr in registers + readlane broadcast
__global__ __launch_bounds__(256) void agg_kernel(const float2* __restrict__ csr,
                                                  const int* __restrict__ offs,
                                                  const float2* __restrict__ tab2,
                                                  const float* __restrict__ new_node,
                                                  float* __restrict__ agg, int N){
  int n = blockIdx.x*4 + (threadIdx.x >> 6);
  int lane = threadIdx.x & 63;
  if (n >= N) return;
  int beg = offs[n], end = offs[n+1];
  float acc = 0.f;
  for (int c = beg; c < end; c += 64){
    int m = end - c; if (m > 64) m = 64;
    float2 pk = csr[c + (lane < m ? lane : 0)];    // coalesced vector load of edge list
    float frv = pk.x;
    int   pkv = __float_as_int(pk.y);
    int q = 0;
    for (; q + 4 <= m; q += 4){
      #pragma unroll
      for (int u=0; u<4; u++){
        int   p  = __builtin_amdgcn_readlane(pkv, q+u);   // scalar broadcast
        float fr = rdl(frv, q+u);
        int idx = p & 4095, s = p >> 12;
        float2 ab = tab2[idx*64 + lane];                  // L2-hot table row
        float nn = new_node[(long)s*64 + lane];           // random 256B row
        acc = fmaf(nn, fmaf(fr, ab.y - ab.x, ab.x), acc);
      }
    }
    for (; q < m; q++){
      int   p  = __builtin_amdgcn_readlane(pkv, q);
      float fr = rdl(frv, q);
      int idx = p & 4095, s = p >> 12;
      float2 ab = tab2[idx*64 + lane];
      float nn = new_node[(long)s*64 + lane];
      acc = fmaf(nn, fmaf(fr, ab.y - ab.x, ab.x), acc);
    }
  }
  agg[(long)n*64 + lane] = acc;
}

// node += sp(agg@nl2.T+b)@nl3.T+b; optionally produce next layer's new_node
template<bool PRODUCE_NN>
__global__ __launch_bounds__(256) void node_update_kernel(float* __restrict__ node,
                                                          const float* __restrict__ agg,
                                                          const float* __restrict__ nl2t,
                                                          const float* __restrict__ nl2_b,
                                                          const float* __restrict__ nl3t,
                                                          const float* __restrict__ nl3_b,
                                                          const float* __restrict__ cw1t_next,
                                                          float* __restrict__ new_node, int N){
  int wid = threadIdx.x >> 6, lane = threadIdx.x & 63;
  int n0 = (blockIdx.x*4 + wid)*4;
  if (n0 >= N) return;
  float a[4], u[4], cacc[4];
  #pragma unroll
  for (int i=0;i<4;i++){
    int n = n0+i < N ? n0+i : N-1;
    a[i] = agg[(long)n*64 + lane];
    u[i] = nl2_b[lane];
  }
  #pragma unroll 16
  for (int k=0;k<DIM;k++){
    float w = nl2t[k*64 + lane];
    #pragma unroll
    for (int i=0;i<4;i++) u[i] = fmaf(rdl(a[i], k), w, u[i]);
  }
  #pragma unroll
  for (int i=0;i<4;i++){ u[i] = sp_f(u[i]); cacc[i] = nl3_b[lane]; }
  #pragma unroll 16
  for (int k=0;k<DIM;k++){
    float w = nl3t[k*64 + lane];
    #pragma unroll
    for (int i=0;i<4;i++) cacc[i] = fmaf(rdl(u[i], k), w, cacc[i]);
  }
  float nv[4];
  #pragma unroll
  for (int i=0;i<4;i++){
    int n = n0+i < N ? n0+i : N-1;
    nv[i] = node[(long)n*64 + lane] + cacc[i];
    if (n0+i < N) node[(long)(n0+i)*64 + lane] = nv[i];
  }
  if (PRODUCE_NN){
    float o[4];
    #pragma unroll
    for (int i=0;i<4;i++) o[i] = 0.f;
    #pragma unroll 16
    for (int k=0;k<DIM;k++){
      float w = cw1t_next[k*64 + lane];
      #pragma unroll
      for (int i=0;i<4;i++) o[i] = fmaf(rdl(nv[i], k), w, o[i]);
    }
    #pragma unroll
    for (int i=0;i<4;i++)
      if (n0+i < N) new_node[(long)(n0+i)*64 + lane] = o[i];
  }
}

// ---------------- heads ----------------

__global__ __launch_bounds__(256) void node_head_kernel(const float* __restrict__ node,
                                                        const int* __restrict__ nidx,
                                                        const float* __restrict__ nt1t,  // [64][32]
                                                        const float* __restrict__ nt1_b,
                                                        const float* __restrict__ nt2_w, // [3][32]
                                                        const float* __restrict__ nt2_b,
                                                        float* __restrict__ out, int NSEL){
  int r = __builtin_amdgcn_readfirstlane(blockIdx.x*4 + (threadIdx.x>>6));
  int lane = threadIdx.x & 63;
  if (r >= NSEL) return;
  long n = nidx[r];
  const float* x = node + n*64;                    // uniform -> s_loads
  float u = 0.f;
  if (lane < 32){
    u = nt1_b[lane];
    #pragma unroll
    for (int k=0;k<DIM;k++) u += x[k]*nt1t[k*32 + lane];
  }
  #pragma unroll
  for (int q=0;q<3;q++){
    float v = (lane < 32) ? u*nt2_w[q*32 + lane] : 0.f;
    #pragma unroll
    for (int o=32;o>=1;o>>=1) v += __shfl_xor(v, o);
    if (lane == 0) out[(long)r*3 + q] = nt2_b[q] + v;
  }
}

__global__ __launch_bounds__(256) void edge_head_kernel(const float* __restrict__ node,
                                                        const int* __restrict__ sidx,
                                                        const int* __restrict__ tidx,
                                                        const float* __restrict__ et1t, // [128][64]
                                                        const float* __restrict__ et1_b,
                                                        const float* __restrict__ et2_w,// [5][64]
                                                        const float* __restrict__ et2_b,
                                                        float* __restrict__ out, int ESEL){
  int wid = threadIdx.x >> 6, lane = threadIdx.x & 63;
  int r0 = (blockIdx.x*4 + wid)*4;
  if (r0 >= ESEL) return;
  float xs[4], xt[4], acc[4];
  #pragma unroll
  for (int i=0;i<4;i++){
    int r = r0+i < ESEL ? r0+i : ESEL-1;
    long s = sidx[r], t = tidx[r];
    xs[i] = node[s*64 + lane];
    xt[i] = node[t*64 + lane];
    acc[i] = et1_b[lane];
  }
  #pragma unroll 16
  for (int k=0;k<DIM;k++){
    float w1 = et1t[k*64 + lane];
    float w2 = et1t[(64+k)*64 + lane];
    #pragma unroll
    for (int i=0;i<4;i++){
      acc[i] = fmaf(rdl(xs[i], k), w1, acc[i]);
      acc[i] = fmaf(rdl(xt[i], k), w2, acc[i]);
    }
  }
  #pragma unroll
  for (int i=0;i<4;i++){
    if (r0+i >= ESEL) break;
    #pragma unroll
    for (int q=0;q<5;q++){
      float v = acc[i]*et2_w[q*64 + lane];
      #pragma unroll
      for (int o=32;o>=1;o>>=1) v += __shfl_xor(v, o);
      if (lane == 0) out[(long)(r0+i)*5 + q] = et2_b[q] + v;
    }
  }
}

// ---------------- launch ----------------

extern "C" void kernel_launch(void* const* d_in, const int* in_sizes, int n_in,
                              void* d_out, int out_size, void* d_ws, size_t ws_size,
                              hipStream_t stream){
  const float* emb      = (const float*)d_in[0];
  const float* dist     = (const float*)d_in[1];
  const float* edge_mask= (const float*)d_in[2];
  const float* conv_w1  = (const float*)d_in[3];
  const float* cf_w1    = (const float*)d_in[4];
  const float* cf_b1    = (const float*)d_in[5];
  const float* cf_w2    = (const float*)d_in[6];
  const float* cf_b2    = (const float*)d_in[7];
  const float* nl2_w    = (const float*)d_in[8];
  const float* nl2_b    = (const float*)d_in[9];
  const float* nl3_w    = (const float*)d_in[10];
  const float* nl3_b    = (const float*)d_in[11];
  const float* nt1_w    = (const float*)d_in[12];
  const float* nt1_b    = (const float*)d_in[13];
  const float* nt2_w    = (const float*)d_in[14];
  const float* nt2_b    = (const float*)d_in[15];
  const float* et1_w    = (const float*)d_in[16];
  const float* et1_b    = (const float*)d_in[17];
  const float* et2_w    = (const float*)d_in[18];
  const float* et2_b    = (const float*)d_in[19];
  const int* node_type  = (const int*)d_in[20];
  const int* src        = (const int*)d_in[21];
  const int* dst        = (const int*)d_in[22];
  const int* sel        = (const int*)d_in[23];
  const int* node_index = (const int*)d_in[24];
  const int* source_index = (const int*)d_in[25];
  const int* target_index = (const int*)d_in[26];

  int E    = in_sizes[1];
  int N    = in_sizes[20];
  int K    = in_sizes[23];
  int NSEL = in_sizes[24];
  int ESEL = in_sizes[25];

  size_t N64 = (size_t)N*64;
  float* p = (float*)d_ws;
  float* node     = p; p += N64;
  float* new_node = p; p += N64;
  float* agg      = p; p += N64;
  float* cw1t     = p; p += 3*4096;
  float* w2t      = p; p += 3*4096;
  float* nl2t     = p; p += 3*4096;
  float* nl3t     = p; p += 3*4096;
  float* et1t     = p; p += 128*64;
  float* nt1t     = p; p += 64*32;
  float* tab2     = p; p += (size_t)3*TABP*2*DIM;
  float2* csr     = (float2*)p; p += 2*(size_t)E;
  int*   counts   = (int*)p; p += (N+1);
  int*   offs     = (int*)p; p += (N+1);
  int*   cursor   = (int*)p; p += N;
  unsigned char* flag = (unsigned char*)p;

  // CSR build + flags
  hipMemsetAsync(counts, 0, (size_t)(N+1)*sizeof(int), stream);
  hist_flag_kernel<<<(E+255)/256, 256, 0, stream>>>(dst, flag, counts, E);
  flag_set_kernel<<<(K+255)/256, 256, 0, stream>>>(sel, flag, K);
  prep_transpose_kernel<<<48, 256, 0, stream>>>(cf_w2, nl3_w, conv_w1, nl2_w, et1_w, nt1_w,
                                                w2t, nl3t, cw1t, nl2t, et1t, nt1t);
  scan_kernel<<<1, 1024, 0, stream>>>(counts, offs, cursor, N);
  scatter_kernel<<<(E+255)/256, 256, 0, stream>>>(dist, src, dst, flag, cursor, csr, E);
  // filter tables (3 layers)
  dim3 tg((TABP+63)/64, 3);
  table_kernel<<<tg, 64, 0, stream>>>(edge_mask, cf_w1, cf_b1, w2t, cf_b2, tab2);

  int nb4  = (N+15)/16;    // 4 waves/block x 4 nodes/wave
  int nb_agg = (N+3)/4;    // 4 waves/block x 1 node/wave
  node_init_nn_kernel<<<nb4, 256, 0, stream>>>(emb, node_type, cw1t, node, new_node, N);
  for (int l=0;l<3;l++){
    agg_kernel<<<nb_agg, 256, 0, stream>>>(csr, offs,
        (const float2*)(tab2 + (size_t)l*TABP*2*DIM), new_node, agg, N);
    if (l < 2)
      node_update_kernel<true><<<nb4, 256, 0, stream>>>(node, agg, nl2t + l*4096, nl2_b + l*64,
          nl3t + l*4096, nl3_b + l*64, cw1t + (l+1)*4096, new_node, N);
    else
      node_update_kernel<false><<<nb4, 256, 0, stream>>>(node, agg, nl2t + l*4096, nl2_b + l*64,
          nl3t + l*4096, nl3_b + l*64, nullptr, nullptr, N);
  }

  node_head_kernel<<<(NSEL+3)/4, 256, 0, stream>>>(node, node_index,
      nt1t, nt1_b, nt2_w, nt2_b, (float*)d_out, NSEL);
  edge_head_kernel<<<(ESEL+15)/16, 256, 0, stream>>>(node, source_index, target_index,
      et1t, et1_b, et2_w, et2_b, (float*)d_out + (size_t)NSEL*3, ESEL);
}

// Round 5
// 543.467 us; speedup vs baseline: 6.0260x; 1.3082x over previous
//
#include <hip/hip_runtime.h>
#include <hip/hip_bf16.h>

#define DIM 64
#define NC 50
#define TABN 2048
#define TABP (TABN + 2)   // rows 0..2047 = interp pairs, 2048 = endpoint h(5), 2049 = mask row

__device__ __forceinline__ float sp_f(float x){
  // torch Softplus(beta=0.5, threshold=14): 2*log(1+exp(0.5x)), linear when 0.5*x>14
  float e = __expf(0.5f*x);
  float s = 2.0f*__logf(1.0f+e);
  return x > 28.0f ? x : s;
}

__device__ __forceinline__ float rdl(float v, int l){
  return __int_as_float(__builtin_amdgcn_readlane(__float_as_int(v), l));
}

// ---------------- CSR build: one atomic pass ----------------

// counts histogram + per-edge rank capture (rank = return of atomicAdd)
__global__ void hist_rank_kernel(const int* __restrict__ dst, int* __restrict__ counts,
                                 int* __restrict__ rank, int E){
  int e = blockIdx.x*256 + threadIdx.x;
  if (e < E) rank[e] = atomicAdd(&counts[dst[e]], 1);
}

// fold masked-edge flag into rank sign bit
__global__ void sel_mark_kernel(const int* __restrict__ sel, unsigned int* __restrict__ rank, int K){
  int id = blockIdx.x*256 + threadIdx.x;
  if (id < K) atomicOr(&rank[sel[id]], 0x80000000u);
}

// single-block exclusive scan of counts -> offs (coalesced tiles, shfl-based)
__global__ __launch_bounds__(1024) void scan_kernel(const int* __restrict__ counts,
                                                    int* __restrict__ offs, int N){
  __shared__ int wexcl[16];
  __shared__ int s_tt;
  __shared__ int s_carry;
  int t = threadIdx.x, lane = t & 63, wid = t >> 6;
  if (t == 0) s_carry = 0;
  for (int base = 0; base < N; base += 1024){
    int i = base + t;
    int v = (i < N) ? counts[i] : 0;
    int x = v;
    #pragma unroll
    for (int off=1; off<64; off<<=1){ int u = __shfl_up(x, off); if (lane >= off) x += u; }
    __syncthreads();
    if (lane == 63) wexcl[wid] = x;
    __syncthreads();
    if (wid == 0 && lane < 16){
      int orig = wexcl[lane];
      int s = orig;
      #pragma unroll
      for (int off=1; off<16; off<<=1){ int u = __shfl_up(s, off); if (lane >= off) s += u; }
      wexcl[lane] = s - orig;
      if (lane == 15) s_tt = s;
    }
    __syncthreads();
    int excl = s_carry + wexcl[wid] + (x - v);
    if (i < N) offs[i] = excl;
    __syncthreads();
    if (t == 0) s_carry += s_tt;
  }
  __syncthreads();
  if (t == 0) offs[N] = s_carry;
}

// dst-sorted edge stream, 4B packed: (src<<16) | code
// code: 16-bit fixed point q = round(t*16), t in [0,2048); masked -> 32784 (idx 2049, fr 0)
__global__ void scatter_kernel(const float* __restrict__ dist,
                               const int* __restrict__ src,
                               const int* __restrict__ dst,
                               const int* __restrict__ rank,
                               const int* __restrict__ offs,
                               unsigned int* __restrict__ csr, int E){
  int e = blockIdx.x*256 + threadIdx.x;
  if (e >= E) return;
  int r = rank[e];
  bool masked = r < 0;
  r &= 0x7FFFFFFF;
  int pos = offs[dst[e]] + r;          // no atomic: rank precomputed
  float d = dist[e];
  float t = fminf(fmaxf(d, 0.f) * ((float)TABN/5.0f), 2047.999f);
  int q = (int)(t*16.f + 0.5f);        // <= 32768
  if (masked) q = (TABN+1)*16;         // 32784
  csr[pos] = ((unsigned int)src[e] << 16) | (unsigned int)q;
}

// ---------------- prep: weight transposes [j][k] -> [k][j] ----------------

__global__ void prep_transpose_kernel(const float* __restrict__ cf_w2,
                                      const float* __restrict__ nl3_w,
                                      const float* __restrict__ conv_w1,
                                      const float* __restrict__ nl2_w,
                                      const float* __restrict__ et1_w,
                                      const float* __restrict__ nt1_w,
                                      float* __restrict__ w2t,
                                      float* __restrict__ nl3t,
                                      float* __restrict__ cw1t,
                                      float* __restrict__ nl2t,
                                      float* __restrict__ et1t,
                                      float* __restrict__ nt1t){
  int id = blockIdx.x*256 + threadIdx.x;
  if (id < 3*4096){
    int i = id >> 12, r = id & 4095;
    int k = r >> 6, j = r & 63;
    int s = i*4096 + j*64 + k;
    w2t[id]  = cf_w2[s];
    nl3t[id] = nl3_w[s];
    cw1t[id] = conv_w1[s];
    nl2t[id] = nl2_w[s];
  }
  if (id < 128*64){
    int k = id >> 6, j = id & 63;
    et1t[id] = et1_w[j*128 + k];   // et1_w is [64][128]
  }
  if (id < 64*32){
    int k = id >> 5, j = id & 31;
    nt1t[id] = nt1_w[j*64 + k];    // nt1_w is [32][64]
  }
}

// ---------------- filter table (bf16 lerp pairs) ----------------
// tabb[row][j] = uint32 { lo16 = bf16(h_row[j]), hi16 = bf16(h_{row+1}[j]) }

__global__ __launch_bounds__(64) void table_kernel(const float* __restrict__ edge_mask,
                                                   const float* __restrict__ cf_w1,
                                                   const float* __restrict__ cf_b1,
                                                   const float* __restrict__ w2t,
                                                   const float* __restrict__ cf_b2,
                                                   __hip_bfloat16* __restrict__ tabb){
  int l = blockIdx.y;
  int p = blockIdx.x*64 + threadIdx.x;
  if (p >= TABP) return;
  float rbf[NC];
  if (p == TABN+1){
    #pragma unroll
    for (int m=0;m<NC;m++) rbf[m] = edge_mask[m];
  } else {
    float d = (float)p * (5.0f/(float)TABN);
    #pragma unroll
    for (int m=0;m<NC;m++){
      float c = (m == NC-1) ? 5.0f : (float)((double)m * (5.0/49.0));
      float df = d - c;
      rbf[m] = __expf((float)(-1.0/(5.0/49.0)) * df * df);
    }
  }
  const float* W1 = cf_w1 + l*DIM*NC;
  const float* B1 = cf_b1 + l*DIM;
  const float* W2 = w2t  + l*DIM*DIM;
  const float* B2 = cf_b2 + l*DIM;
  float h[DIM];
  #pragma unroll
  for (int j=0;j<DIM;j++) h[j] = B2[j];
  for (int k=0;k<DIM;k++){
    float t = B1[k];
    const float* w1r = W1 + k*NC;
    #pragma unroll
    for (int m=0;m<NC;m++) t += rbf[m]*w1r[m];
    float spt = sp_f(t);
    const float* w2r = W2 + k*DIM;
    #pragma unroll
    for (int j=0;j<DIM;j++) h[j] += spt*w2r[j];
  }
  __hip_bfloat16* T = tabb + ((size_t)l*TABP + p)*2*DIM;
  #pragma unroll
  for (int j=0;j<DIM;j++) T[2*j] = __float2bfloat16(h[j]);          // own .lo
  if (p >= 1){
    __hip_bfloat16* Tp = T - 2*DIM;
    #pragma unroll
    for (int j=0;j<DIM;j++) Tp[2*j+1] = __float2bfloat16(h[j]);     // prev .hi
  }
  if (p == TABN+1){
    #pragma unroll
    for (int j=0;j<DIM;j++) T[2*j+1] = __float2bfloat16(h[j]);      // mask row: (hm,hm)
  }
}

// ---------------- node-side kernels (wave = 4 nodes, lane = feature) ----------------

// node = emb[node_type]; new_node(bf16) = node @ W1[0]^T
__global__ __launch_bounds__(256) void node_init_nn_kernel(const float* __restrict__ emb,
                                                           const int* __restrict__ node_type,
                                                           const float* __restrict__ cw1t,
                                                           float* __restrict__ node,
                                                           __hip_bfloat16* __restrict__ nnb, int N){
  int wid = threadIdx.x >> 6, lane = threadIdx.x & 63;
  int n0 = (blockIdx.x*4 + wid)*4;
  if (n0 >= N) return;
  float nv[4], o[4];
  #pragma unroll
  for (int i=0;i<4;i++){
    int n = n0+i < N ? n0+i : N-1;
    nv[i] = emb[(long)node_type[n]*64 + lane];
    o[i] = 0.f;
  }
  #pragma unroll 16
  for (int k=0;k<DIM;k++){
    float w = cw1t[k*64 + lane];
    #pragma unroll
    for (int i=0;i<4;i++) o[i] = fmaf(rdl(nv[i], k), w, o[i]);
  }
  #pragma unroll
  for (int i=0;i<4;i++){
    if (n0+i < N){
      node[(long)(n0+i)*64 + lane] = nv[i];
      nnb[(long)(n0+i)*64 + lane] = __float2bfloat16(o[i]);
    }
  }
}

// gather-aggregate: wave = 1 dst node, lane = feature; 4B csr, bf16 table + new_node
__global__ __launch_bounds__(256) void agg_kernel(const unsigned int* __restrict__ csr,
                                                  const int* __restrict__ offs,
                                                  const unsigned int* __restrict__ tab,   // [TABP][64] u32
                                                  const unsigned short* __restrict__ nnb, // bf16 bits
                                                  float* __restrict__ agg, int N){
  int n = blockIdx.x*4 + (threadIdx.x >> 6);
  int lane = threadIdx.x & 63;
  if (n >= N) return;
  int beg = offs[n], end = offs[n+1];
  float acc = 0.f;
  for (int c = beg; c < end; c += 64){
    int m = end - c; if (m > 64) m = 64;
    unsigned int pkv = csr[c + (lane < m ? lane : 0)];   // coalesced edge-list load
    int q = 0;
    for (; q + 4 <= m; q += 4){
      #pragma unroll
      for (int u=0; u<4; u++){
        unsigned int p = (unsigned int)__builtin_amdgcn_readlane((int)pkv, q+u); // SGPR
        int code = p & 0xFFFF, s = p >> 16;
        int idx = code >> 4;
        float fr = (float)(code & 15) * 0.0625f;
        unsigned int tv = tab[idx*64 + lane];            // L2-hot bf16 pair
        float a = __uint_as_float(tv << 16);
        float b = __uint_as_float(tv & 0xFFFF0000u);
        float nn = __uint_as_float(((unsigned int)nnb[(long)s*64 + lane]) << 16);
        acc = fmaf(nn, fmaf(fr, b - a, a), acc);
      }
    }
    for (; q < m; q++){
      unsigned int p = (unsigned int)__builtin_amdgcn_readlane((int)pkv, q);
      int code = p & 0xFFFF, s = p >> 16;
      int idx = code >> 4;
      float fr = (float)(code & 15) * 0.0625f;
      unsigned int tv = tab[idx*64 + lane];
      float a = __uint_as_float(tv << 16);
      float b = __uint_as_float(tv & 0xFFFF0000u);
      float nn = __uint_as_float(((unsigned int)nnb[(long)s*64 + lane]) << 16);
      acc = fmaf(nn, fmaf(fr, b - a, a), acc);
    }
  }
  agg[(long)n*64 + lane] = acc;
}

// node += sp(agg@nl2.T+b)@nl3.T+b; optionally produce next layer's new_node (bf16)
template<bool PRODUCE_NN>
__global__ __launch_bounds__(256) void node_update_kernel(float* __restrict__ node,
                                                          const float* __restrict__ agg,
                                                          const float* __restrict__ nl2t,
                                                          const float* __restrict__ nl2_b,
                                                          const float* __restrict__ nl3t,
                                                          const float* __restrict__ nl3_b,
                                                          const float* __restrict__ cw1t_next,
                                                          __hip_bfloat16* __restrict__ nnb, int N){
  int wid = threadIdx.x >> 6, lane = threadIdx.x & 63;
  int n0 = (blockIdx.x*4 + wid)*4;
  if (n0 >= N) return;
  float a[4], u[4], cacc[4];
  #pragma unroll
  for (int i=0;i<4;i++){
    int n = n0+i < N ? n0+i : N-1;
    a[i] = agg[(long)n*64 + lane];
    u[i] = nl2_b[lane];
  }
  #pragma unroll 16
  for (int k=0;k<DIM;k++){
    float w = nl2t[k*64 + lane];
    #pragma unroll
    for (int i=0;i<4;i++) u[i] = fmaf(rdl(a[i], k), w, u[i]);
  }
  #pragma unroll
  for (int i=0;i<4;i++){ u[i] = sp_f(u[i]); cacc[i] = nl3_b[lane]; }
  #pragma unroll 16
  for (int k=0;k<DIM;k++){
    float w = nl3t[k*64 + lane];
    #pragma unroll
    for (int i=0;i<4;i++) cacc[i] = fmaf(rdl(u[i], k), w, cacc[i]);
  }
  float nv[4];
  #pragma unroll
  for (int i=0;i<4;i++){
    int n = n0+i < N ? n0+i : N-1;
    nv[i] = node[(long)n*64 + lane] + cacc[i];
    if (n0+i < N) node[(long)(n0+i)*64 + lane] = nv[i];
  }
  if (PRODUCE_NN){
    float o[4];
    #pragma unroll
    for (int i=0;i<4;i++) o[i] = 0.f;
    #pragma unroll 16
    for (int k=0;k<DIM;k++){
      float w = cw1t_next[k*64 + lane];
      #pragma unroll
      for (int i=0;i<4;i++) o[i] = fmaf(rdl(nv[i], k), w, o[i]);
    }
    #pragma unroll
    for (int i=0;i<4;i++)
      if (n0+i < N) nnb[(long)(n0+i)*64 + lane] = __float2bfloat16(o[i]);
  }
}

// ---------------- heads ----------------

__global__ __launch_bounds__(256) void node_head_kernel(const float* __restrict__ node,
                                                        const int* __restrict__ nidx,
                                                        const float* __restrict__ nt1t,  // [64][32]
                                                        const float* __restrict__ nt1_b,
                                                        const float* __restrict__ nt2_w, // [3][32]
                                                        const float* __restrict__ nt2_b,
                                                        float* __restrict__ out, int NSEL){
  int r = __builtin_amdgcn_readfirstlane(blockIdx.x*4 + (threadIdx.x>>6));
  int lane = threadIdx.x & 63;
  if (r >= NSEL) return;
  long n = nidx[r];
  const float* x = node + n*64;                    // uniform -> s_loads
  float u = 0.f;
  if (lane < 32){
    u = nt1_b[lane];
    #pragma unroll
    for (int k=0;k<DIM;k++) u += x[k]*nt1t[k*32 + lane];
  }
  #pragma unroll
  for (int q=0;q<3;q++){
    float v = (lane < 32) ? u*nt2_w[q*32 + lane] : 0.f;
    #pragma unroll
    for (int o=32;o>=1;o>>=1) v += __shfl_xor(v, o);
    if (lane == 0) out[(long)r*3 + q] = nt2_b[q] + v;
  }
}

__global__ __launch_bounds__(256) void edge_head_kernel(const float* __restrict__ node,
                                                        const int* __restrict__ sidx,
                                                        const int* __restrict__ tidx,
                                                        const float* __restrict__ et1t, // [128][64]
                                                        const float* __restrict__ et1_b,
                                                        const float* __restrict__ et2_w,// [5][64]
                                                        const float* __restrict__ et2_b,
                                                        float* __restrict__ out, int ESEL){
  int wid = threadIdx.x >> 6, lane = threadIdx.x & 63;
  int r0 = (blockIdx.x*4 + wid)*4;
  if (r0 >= ESEL) return;
  float xs[4], xt[4], acc[4];
  #pragma unroll
  for (int i=0;i<4;i++){
    int r = r0+i < ESEL ? r0+i : ESEL-1;
    long s = sidx[r], t = tidx[r];
    xs[i] = node[s*64 + lane];
    xt[i] = node[t*64 + lane];
    acc[i] = et1_b[lane];
  }
  #pragma unroll 16
  for (int k=0;k<DIM;k++){
    float w1 = et1t[k*64 + lane];
    float w2 = et1t[(64+k)*64 + lane];
    #pragma unroll
    for (int i=0;i<4;i++){
      acc[i] = fmaf(rdl(xs[i], k), w1, acc[i]);
      acc[i] = fmaf(rdl(xt[i], k), w2, acc[i]);
    }
  }
  #pragma unroll
  for (int i=0;i<4;i++){
    if (r0+i >= ESEL) break;
    #pragma unroll
    for (int q=0;q<5;q++){
      float v = acc[i]*et2_w[q*64 + lane];
      #pragma unroll
      for (int o=32;o>=1;o>>=1) v += __shfl_xor(v, o);
      if (lane == 0) out[(long)(r0+i)*5 + q] = et2_b[q] + v;
    }
  }
}

// ---------------- launch ----------------

extern "C" void kernel_launch(void* const* d_in, const int* in_sizes, int n_in,
                              void* d_out, int out_size, void* d_ws, size_t ws_size,
                              hipStream_t stream){
  const float* emb      = (const float*)d_in[0];
  const float* dist     = (const float*)d_in[1];
  const float* edge_mask= (const float*)d_in[2];
  const float* conv_w1  = (const float*)d_in[3];
  const float* cf_w1    = (const float*)d_in[4];
  const float* cf_b1    = (const float*)d_in[5];
  const float* cf_w2    = (const float*)d_in[6];
  const float* cf_b2    = (const float*)d_in[7];
  const float* nl2_w    = (const float*)d_in[8];
  const float* nl2_b    = (const float*)d_in[9];
  const float* nl3_w    = (const float*)d_in[10];
  const float* nl3_b    = (const float*)d_in[11];
  const float* nt1_w    = (const float*)d_in[12];
  const float* nt1_b    = (const float*)d_in[13];
  const float* nt2_w    = (const float*)d_in[14];
  const float* nt2_b    = (const float*)d_in[15];
  const float* et1_w    = (const float*)d_in[16];
  const float* et1_b    = (const float*)d_in[17];
  const float* et2_w    = (const float*)d_in[18];
  const float* et2_b    = (const float*)d_in[19];
  const int* node_type  = (const int*)d_in[20];
  const int* src        = (const int*)d_in[21];
  const int* dst        = (const int*)d_in[22];
  const int* sel        = (const int*)d_in[23];
  const int* node_index = (const int*)d_in[24];
  const int* source_index = (const int*)d_in[25];
  const int* target_index = (const int*)d_in[26];

  int E    = in_sizes[1];
  int N    = in_sizes[20];
  int K    = in_sizes[23];
  int NSEL = in_sizes[24];
  int ESEL = in_sizes[25];

  size_t N64 = (size_t)N*64;
  float* p = (float*)d_ws;
  float* node     = p; p += N64;
  float* agg      = p; p += N64;
  __hip_bfloat16* nnb = (__hip_bfloat16*)p; p += N64/2;        // bf16 new_node
  float* cw1t     = p; p += 3*4096;
  float* w2t      = p; p += 3*4096;
  float* nl2t     = p; p += 3*4096;
  float* nl3t     = p; p += 3*4096;
  float* et1t     = p; p += 128*64;
  float* nt1t     = p; p += 64*32;
  __hip_bfloat16* tabb = (__hip_bfloat16*)p; p += (size_t)3*TABP*DIM; // 3 layers x [TABP][64] u32
  unsigned int* csr = (unsigned int*)p; p += E;
  int*   rank     = (int*)p; p += E;
  int*   counts   = (int*)p; p += (N+1);
  int*   offs     = (int*)p; p += (N+1);

  // CSR build (single atomic pass: ranks captured in hist)
  hipMemsetAsync(counts, 0, (size_t)N*sizeof(int), stream);
  hist_rank_kernel<<<(E+255)/256, 256, 0, stream>>>(dst, counts, rank, E);
  sel_mark_kernel<<<(K+255)/256, 256, 0, stream>>>(sel, (unsigned int*)rank, K);
  prep_transpose_kernel<<<48, 256, 0, stream>>>(cf_w2, nl3_w, conv_w1, nl2_w, et1_w, nt1_w,
                                                w2t, nl3t, cw1t, nl2t, et1t, nt1t);
  scan_kernel<<<1, 1024, 0, stream>>>(counts, offs, N);
  scatter_kernel<<<(E+255)/256, 256, 0, stream>>>(dist, src, dst, rank, offs, csr, E);
  // filter tables (3 layers, bf16 lerp pairs)
  dim3 tg((TABP+63)/64, 3);
  table_kernel<<<tg, 64, 0, stream>>>(edge_mask, cf_w1, cf_b1, w2t, cf_b2, tabb);

  int nb4  = (N+15)/16;    // 4 waves/block x 4 nodes/wave
  int nb_agg = (N+3)/4;    // 4 waves/block x 1 node/wave
  node_init_nn_kernel<<<nb4, 256, 0, stream>>>(emb, node_type, cw1t, node, nnb, N);
  for (int l=0;l<3;l++){
    agg_kernel<<<nb_agg, 256, 0, stream>>>(csr, offs,
        (const unsigned int*)(tabb + (size_t)l*TABP*2*DIM),
        (const unsigned short*)nnb, agg, N);
    if (l < 2)
      node_update_kernel<true><<<nb4, 256, 0, stream>>>(node, agg, nl2t + l*4096, nl2_b + l*64,
          nl3t + l*4096, nl3_b + l*64, cw1t + (l+1)*4096, nnb, N);
    else
      node_update_kernel<false><<<nb4, 256, 0, stream>>>(node, agg, nl2t + l*4096, nl2_b + l*64,
          nl3t + l*4096, nl3_b + l*64, nullptr, nullptr, N);
  }

  node_head_kernel<<<(NSEL+3)/4, 256, 0, stream>>>(node, node_index,
      nt1t, nt1_b, nt2_w, nt2_b, (float*)d_out, NSEL);
  edge_head_kernel<<<(ESEL+15)/16, 256, 0, stream>>>(node, source_index, target_index,
      et1t, et1_b, et2_w, et2_b, (float*)d_out + (size_t)NSEL*3, ESEL);
}

// Round 6
// 441.638 us; speedup vs baseline: 7.4154x; 1.2306x over previous
//
#include <hip/hip_runtime.h>
#include <hip/hip_bf16.h>

#define DIM 64
#define NC 50
#define TABN 2048
#define TABP (TABN + 2)   // rows 0..2047 = interp pairs, 2048 = endpoint h(5), 2049 = mask row

__device__ __forceinline__ float sp_f(float x){
  // torch Softplus(beta=0.5, threshold=14): 2*log(1+exp(0.5x)), linear when 0.5*x>14
  float e = __expf(0.5f*x);
  float s = 2.0f*__logf(1.0f+e);
  return x > 28.0f ? x : s;
}

__device__ __forceinline__ float rdl(float v, int l){
  return __int_as_float(__builtin_amdgcn_readlane(__float_as_int(v), l));
}

// ---------------- CSR build: XCD-local atomic pass ----------------

// counts8[xcd][n] histogram with L2-local (workgroup-scope) atomics + rank capture.
// Each XCD owns a private slice -> no cross-die atomic coherence traffic.
__global__ void hist_rank_kernel(const int* __restrict__ dst,
                                 unsigned int* __restrict__ counts8,
                                 unsigned int* __restrict__ rank, int N, int E){
  unsigned int xcc;
  asm volatile("s_getreg_b32 %0, hwreg(HW_REG_XCC_ID)" : "=s"(xcc));
  xcc &= 7u;
  int e = blockIdx.x*256 + threadIdx.x;
  if (e >= E) return;
  int d = dst[e];
  unsigned int r = __hip_atomic_fetch_add(&counts8[xcc*(unsigned)N + (unsigned)d], 1u,
                                          __ATOMIC_RELAXED, __HIP_MEMORY_SCOPE_WORKGROUP);
  rank[e] = (xcc << 24) | r;          // local rank < 2^24
}

// fold masked-edge flag into rank bit 31
__global__ void sel_mark_kernel(const int* __restrict__ sel, unsigned int* __restrict__ rank, int K){
  int id = blockIdx.x*256 + threadIdx.x;
  if (id < K) atomicOr(&rank[sel[id]], 0x80000000u);
}

// per node: exclusive prefix over the 8 XCD slices (in place) + total
__global__ void xprefix_kernel(unsigned int* __restrict__ counts8,
                               int* __restrict__ total, int N){
  int n = blockIdx.x*256 + threadIdx.x;
  if (n >= N) return;
  unsigned int t = 0;
  #pragma unroll
  for (int x=0;x<8;x++){
    unsigned int c = counts8[(unsigned)x*N + n];
    counts8[(unsigned)x*N + n] = t;
    t += c;
  }
  total[n] = (int)t;
}

// block-level exclusive scan: intra[n] + per-block totals
__global__ __launch_bounds__(256) void scan1_kernel(const int* __restrict__ total,
                                                    int* __restrict__ intra,
                                                    int* __restrict__ bsum, int N){
  __shared__ int wtot[4];
  int tid = threadIdx.x, lane = tid & 63, wid = tid >> 6;
  int n = blockIdx.x*256 + tid;
  int v = (n < N) ? total[n] : 0;
  int x = v;
  #pragma unroll
  for (int off=1; off<64; off<<=1){ int u = __shfl_up(x, off); if (lane >= off) x += u; }
  if (lane == 63) wtot[wid] = x;
  __syncthreads();
  int wb = 0;
  #pragma unroll
  for (int q=0;q<4;q++) wb += (q < wid) ? wtot[q] : 0;
  if (n < N) intra[n] = wb + x - v;
  if (tid == 255) bsum[blockIdx.x] = wb + x;
}

// single-block exclusive scan of block totals (tiles of 256 with carry)
__global__ __launch_bounds__(256) void scan2_kernel(int* __restrict__ bsum, int nb){
  __shared__ int wtot[4];
  __shared__ int carry;
  int tid = threadIdx.x, lane = tid & 63, wid = tid >> 6;
  if (tid == 0) carry = 0;
  __syncthreads();
  for (int base = 0; base < nb; base += 256){
    int i = base + tid;
    int v = (i < nb) ? bsum[i] : 0;
    int x = v;
    #pragma unroll
    for (int off=1; off<64; off<<=1){ int u = __shfl_up(x, off); if (lane >= off) x += u; }
    if (lane == 63) wtot[wid] = x;
    __syncthreads();
    int wb = 0;
    #pragma unroll
    for (int q=0;q<4;q++) wb += (q < wid) ? wtot[q] : 0;
    int tt = wtot[0] + wtot[1] + wtot[2] + wtot[3];
    if (i < nb) bsum[i] = carry + wb + x - v;
    __syncthreads();
    if (tid == 0) carry += tt;
    __syncthreads();
  }
}

__global__ void scan3_kernel(const int* __restrict__ intra, const int* __restrict__ bsum,
                             int* __restrict__ offs, int N, int E){
  int n = blockIdx.x*256 + threadIdx.x;
  if (n < N) offs[n] = bsum[n >> 8] + intra[n];
  else if (n == N) offs[N] = E;
}

// dst-sorted edge stream, 4B packed: (src<<16) | code
// code: 16-bit fixed point q = round(t*16), t in [0,2048]; masked -> (TABN+1)*16
__global__ void scatter_kernel(const float* __restrict__ dist,
                               const int* __restrict__ src,
                               const int* __restrict__ dst,
                               const unsigned int* __restrict__ rank,
                               const int* __restrict__ offs,
                               const unsigned int* __restrict__ counts8,  // xcd prefixes
                               unsigned int* __restrict__ csr, int N, int E){
  int e = blockIdx.x*256 + threadIdx.x;
  if (e >= E) return;
  unsigned int rv = rank[e];
  bool masked = (rv >> 31) != 0;
  int xcc = (rv >> 24) & 7;
  int lr  = rv & 0xFFFFFF;
  int d = dst[e];
  int pos = offs[d] + (int)counts8[(unsigned)xcc*N + (unsigned)d] + lr;
  float dd = dist[e];
  float t = fminf(fmaxf(dd, 0.f) * ((float)TABN/5.0f), 2047.999f);
  int q = (int)(t*16.f + 0.5f);
  if (masked) q = (TABN+1)*16;
  csr[pos] = ((unsigned int)src[e] << 16) | (unsigned int)q;
}

// ---------------- prep: weight transposes [j][k] -> [k][j] ----------------

__global__ void prep_transpose_kernel(const float* __restrict__ cf_w2,
                                      const float* __restrict__ nl3_w,
                                      const float* __restrict__ conv_w1,
                                      const float* __restrict__ nl2_w,
                                      const float* __restrict__ et1_w,
                                      const float* __restrict__ nt1_w,
                                      const float* __restrict__ cf_w1,
                                      float* __restrict__ w2t,
                                      float* __restrict__ nl3t,
                                      float* __restrict__ cw1t,
                                      float* __restrict__ nl2t,
                                      float* __restrict__ et1t,
                                      float* __restrict__ nt1t,
                                      float* __restrict__ w1t){
  int id = blockIdx.x*256 + threadIdx.x;
  if (id < 3*4096){
    int i = id >> 12, r = id & 4095;
    int k = r >> 6, j = r & 63;
    int s = i*4096 + j*64 + k;
    w2t[id]  = cf_w2[s];
    nl3t[id] = nl3_w[s];
    cw1t[id] = conv_w1[s];
    nl2t[id] = nl2_w[s];
  }
  if (id < 128*64){
    int k = id >> 6, j = id & 63;
    et1t[id] = et1_w[j*128 + k];   // et1_w is [64][128]
  }
  if (id < 64*32){
    int k = id >> 5, j = id & 31;
    nt1t[id] = nt1_w[j*64 + k];    // nt1_w is [32][64]
  }
  if (id < 3*NC*DIM){              // cf_w1 [3][64][50] -> w1t [3][50][64]
    int l = id / (NC*DIM);
    int r = id - l*(NC*DIM);
    int m = r >> 6, k = r & 63;
    w1t[id] = cf_w1[l*DIM*NC + k*NC + m];
  }
}

// ---------------- filter table (bf16 lerp pairs), wave = row, lane = feature ----------------
// tabb[row][j] = uint32 { lo16 = bf16(h_row[j]), hi16 = bf16(h_{row+1}[j]) }

__global__ __launch_bounds__(256) void table_kernel(const float* __restrict__ edge_mask,
                                                    const float* __restrict__ w1t,   // [3][50][64]
                                                    const float* __restrict__ cf_b1,
                                                    const float* __restrict__ w2t,   // [3][64][64]
                                                    const float* __restrict__ cf_b2,
                                                    __hip_bfloat16* __restrict__ tabb){
  int row = blockIdx.x*4 + (threadIdx.x >> 6);
  if (row >= 3*TABP) return;
  int l = row / TABP, p = row - l*TABP;
  int lane = threadIdx.x & 63;
  // rbf value owned by lane m (m < 50)
  float rbfv = 0.f;
  if (lane < NC){
    if (p == TABN+1) rbfv = edge_mask[lane];
    else {
      float d = (float)p * (5.0f/(float)TABN);
      float c = (lane == NC-1) ? 5.0f : (float)((double)lane * (5.0/49.0));
      float df = d - c;
      rbfv = __expf((float)(-1.0/(5.0/49.0)) * df * df);
    }
  }
  const float* W1 = w1t + l*NC*DIM;
  float t = cf_b1[l*DIM + lane];
  #pragma unroll 10
  for (int m=0;m<NC;m++)
    t = fmaf(rdl(rbfv, m), W1[m*64 + lane], t);
  float su = sp_f(t);
  const float* W2 = w2t + l*DIM*DIM;
  float h = cf_b2[l*DIM + lane];
  #pragma unroll 16
  for (int k=0;k<DIM;k++)
    h = fmaf(rdl(su, k), W2[k*64 + lane], h);
  __hip_bfloat16 hb = __float2bfloat16(h);
  __hip_bfloat16* T = tabb + ((size_t)l*TABP + p)*2*DIM;
  T[2*lane] = hb;                            // own row .lo
  if (p >= 1) (T - 2*DIM)[2*lane + 1] = hb;  // previous row .hi (disjoint bytes)
  if (p == TABN+1) T[2*lane + 1] = hb;       // mask row: (hm, hm)
}

// ---------------- node-side kernels (wave = 4 nodes, lane = feature) ----------------

__global__ __launch_bounds__(256) void node_init_nn_kernel(const float* __restrict__ emb,
                                                           const int* __restrict__ node_type,
                                                           const float* __restrict__ cw1t,
                                                           float* __restrict__ node,
                                                           __hip_bfloat16* __restrict__ nnb, int N){
  int wid = threadIdx.x >> 6, lane = threadIdx.x & 63;
  int n0 = (blockIdx.x*4 + wid)*4;
  if (n0 >= N) return;
  float nv[4], o[4];
  #pragma unroll
  for (int i=0;i<4;i++){
    int n = n0+i < N ? n0+i : N-1;
    nv[i] = emb[(long)node_type[n]*64 + lane];
    o[i] = 0.f;
  }
  #pragma unroll 16
  for (int k=0;k<DIM;k++){
    float w = cw1t[k*64 + lane];
    #pragma unroll
    for (int i=0;i<4;i++) o[i] = fmaf(rdl(nv[i], k), w, o[i]);
  }
  #pragma unroll
  for (int i=0;i<4;i++){
    if (n0+i < N){
      node[(long)(n0+i)*64 + lane] = nv[i];
      nnb[(long)(n0+i)*64 + lane] = __float2bfloat16(o[i]);
    }
  }
}

// gather-aggregate: wave = 1 dst node, lane = feature; 4B csr, bf16 table + new_node
__global__ __launch_bounds__(256) void agg_kernel(const unsigned int* __restrict__ csr,
                                                  const int* __restrict__ offs,
                                                  const unsigned int* __restrict__ tab,   // [TABP][64] u32
                                                  const unsigned short* __restrict__ nnb, // bf16 bits
                                                  float* __restrict__ agg, int N){
  int n = blockIdx.x*4 + (threadIdx.x >> 6);
  int lane = threadIdx.x & 63;
  if (n >= N) return;
  int beg = offs[n], end = offs[n+1];
  float acc = 0.f;
  for (int c = beg; c < end; c += 64){
    int m = end - c; if (m > 64) m = 64;
    unsigned int pkv = csr[c + (lane < m ? lane : 0)];   // coalesced edge-list load
    int q = 0;
    for (; q + 4 <= m; q += 4){
      #pragma unroll
      for (int u=0; u<4; u++){
        unsigned int p = (unsigned int)__builtin_amdgcn_readlane((int)pkv, q+u); // SGPR
        int code = p & 0xFFFF, s = p >> 16;
        int idx = code >> 4;
        float fr = (float)(code & 15) * 0.0625f;
        unsigned int tv = tab[idx*64 + lane];            // L2-hot bf16 pair
        float a = __uint_as_float(tv << 16);
        float b = __uint_as_float(tv & 0xFFFF0000u);
        float nn = __uint_as_float(((unsigned int)nnb[(long)s*64 + lane]) << 16);
        acc = fmaf(nn, fmaf(fr, b - a, a), acc);
      }
    }
    for (; q < m; q++){
      unsigned int p = (unsigned int)__builtin_amdgcn_readlane((int)pkv, q);
      int code = p & 0xFFFF, s = p >> 16;
      int idx = code >> 4;
      float fr = (float)(code & 15) * 0.0625f;
      unsigned int tv = tab[idx*64 + lane];
      float a = __uint_as_float(tv << 16);
      float b = __uint_as_float(tv & 0xFFFF0000u);
      float nn = __uint_as_float(((unsigned int)nnb[(long)s*64 + lane]) << 16);
      acc = fmaf(nn, fmaf(fr, b - a, a), acc);
    }
  }
  agg[(long)n*64 + lane] = acc;
}

// node += sp(agg@nl2.T+b)@nl3.T+b; optionally produce next layer's new_node (bf16)
template<bool PRODUCE_NN>
__global__ __launch_bounds__(256) void node_update_kernel(float* __restrict__ node,
                                                          const float* __restrict__ agg,
                                                          const float* __restrict__ nl2t,
                                                          const float* __restrict__ nl2_b,
                                                          const float* __restrict__ nl3t,
                                                          const float* __restrict__ nl3_b,
                                                          const float* __restrict__ cw1t_next,
                                                          __hip_bfloat16* __restrict__ nnb, int N){
  int wid = threadIdx.x >> 6, lane = threadIdx.x & 63;
  int n0 = (blockIdx.x*4 + wid)*4;
  if (n0 >= N) return;
  float a[4], u[4], cacc[4];
  #pragma unroll
  for (int i=0;i<4;i++){
    int n = n0+i < N ? n0+i : N-1;
    a[i] = agg[(long)n*64 + lane];
    u[i] = nl2_b[lane];
  }
  #pragma unroll 16
  for (int k=0;k<DIM;k++){
    float w = nl2t[k*64 + lane];
    #pragma unroll
    for (int i=0;i<4;i++) u[i] = fmaf(rdl(a[i], k), w, u[i]);
  }
  #pragma unroll
  for (int i=0;i<4;i++){ u[i] = sp_f(u[i]); cacc[i] = nl3_b[lane]; }
  #pragma unroll 16
  for (int k=0;k<DIM;k++){
    float w = nl3t[k*64 + lane];
    #pragma unroll
    for (int i=0;i<4;i++) cacc[i] = fmaf(rdl(u[i], k), w, cacc[i]);
  }
  float nv[4];
  #pragma unroll
  for (int i=0;i<4;i++){
    int n = n0+i < N ? n0+i : N-1;
    nv[i] = node[(long)n*64 + lane] + cacc[i];
    if (n0+i < N) node[(long)(n0+i)*64 + lane] = nv[i];
  }
  if (PRODUCE_NN){
    float o[4];
    #pragma unroll
    for (int i=0;i<4;i++) o[i] = 0.f;
    #pragma unroll 16
    for (int k=0;k<DIM;k++){
      float w = cw1t_next[k*64 + lane];
      #pragma unroll
      for (int i=0;i<4;i++) o[i] = fmaf(rdl(nv[i], k), w, o[i]);
    }
    #pragma unroll
    for (int i=0;i<4;i++)
      if (n0+i < N) nnb[(long)(n0+i)*64 + lane] = __float2bfloat16(o[i]);
  }
}

// ---------------- heads ----------------

__global__ __launch_bounds__(256) void node_head_kernel(const float* __restrict__ node,
                                                        const int* __restrict__ nidx,
                                                        const float* __restrict__ nt1t,  // [64][32]
                                                        const float* __restrict__ nt1_b,
                                                        const float* __restrict__ nt2_w, // [3][32]
                                                        const float* __restrict__ nt2_b,
                                                        float* __restrict__ out, int NSEL){
  int r = __builtin_amdgcn_readfirstlane(blockIdx.x*4 + (threadIdx.x>>6));
  int lane = threadIdx.x & 63;
  if (r >= NSEL) return;
  long n = nidx[r];
  const float* x = node + n*64;                    // uniform -> s_loads
  float u = 0.f;
  if (lane < 32){
    u = nt1_b[lane];
    #pragma unroll
    for (int k=0;k<DIM;k++) u += x[k]*nt1t[k*32 + lane];
  }
  #pragma unroll
  for (int q=0;q<3;q++){
    float v = (lane < 32) ? u*nt2_w[q*32 + lane] : 0.f;
    #pragma unroll
    for (int o=32;o>=1;o>>=1) v += __shfl_xor(v, o);
    if (lane == 0) out[(long)r*3 + q] = nt2_b[q] + v;
  }
}

__global__ __launch_bounds__(256) void edge_head_kernel(const float* __restrict__ node,
                                                        const int* __restrict__ sidx,
                                                        const int* __restrict__ tidx,
                                                        const float* __restrict__ et1t, // [128][64]
                                                        const float* __restrict__ et1_b,
                                                        const float* __restrict__ et2_w,// [5][64]
                                                        const float* __restrict__ et2_b,
                                                        float* __restrict__ out, int ESEL){
  int wid = threadIdx.x >> 6, lane = threadIdx.x & 63;
  int r0 = (blockIdx.x*4 + wid)*4;
  if (r0 >= ESEL) return;
  float xs[4], xt[4], acc[4];
  #pragma unroll
  for (int i=0;i<4;i++){
    int r = r0+i < ESEL ? r0+i : ESEL-1;
    long s = sidx[r], t = tidx[r];
    xs[i] = node[s*64 + lane];
    xt[i] = node[t*64 + lane];
    acc[i] = et1_b[lane];
  }
  #pragma unroll 16
  for (int k=0;k<DIM;k++){
    float w1 = et1t[k*64 + lane];
    float w2 = et1t[(64+k)*64 + lane];
    #pragma unroll
    for (int i=0;i<4;i++){
      acc[i] = fmaf(rdl(xs[i], k), w1, acc[i]);
      acc[i] = fmaf(rdl(xt[i], k), w2, acc[i]);
    }
  }
  #pragma unroll
  for (int i=0;i<4;i++){
    if (r0+i >= ESEL) break;
    #pragma unroll
    for (int q=0;q<5;q++){
      float v = acc[i]*et2_w[q*64 + lane];
      #pragma unroll
      for (int o=32;o>=1;o>>=1) v += __shfl_xor(v, o);
      if (lane == 0) out[(long)(r0+i)*5 + q] = et2_b[q] + v;
    }
  }
}

// ---------------- launch ----------------

extern "C" void kernel_launch(void* const* d_in, const int* in_sizes, int n_in,
                              void* d_out, int out_size, void* d_ws, size_t ws_size,
                              hipStream_t stream){
  const float* emb      = (const float*)d_in[0];
  const float* dist     = (const float*)d_in[1];
  const float* edge_mask= (const float*)d_in[2];
  const float* conv_w1  = (const float*)d_in[3];
  const float* cf_w1    = (const float*)d_in[4];
  const float* cf_b1    = (const float*)d_in[5];
  const float* cf_w2    = (const float*)d_in[6];
  const float* cf_b2    = (const float*)d_in[7];
  const float* nl2_w    = (const float*)d_in[8];
  const float* nl2_b    = (const float*)d_in[9];
  const float* nl3_w    = (const float*)d_in[10];
  const float* nl3_b    = (const float*)d_in[11];
  const float* nt1_w    = (const float*)d_in[12];
  const float* nt1_b    = (const float*)d_in[13];
  const float* nt2_w    = (const float*)d_in[14];
  const float* nt2_b    = (const float*)d_in[15];
  const float* et1_w    = (const float*)d_in[16];
  const float* et1_b    = (const float*)d_in[17];
  const float* et2_w    = (const float*)d_in[18];
  const float* et2_b    = (const float*)d_in[19];
  const int* node_type  = (const int*)d_in[20];
  const int* src        = (const int*)d_in[21];
  const int* dst        = (const int*)d_in[22];
  const int* sel        = (const int*)d_in[23];
  const int* node_index = (const int*)d_in[24];
  const int* source_index = (const int*)d_in[25];
  const int* target_index = (const int*)d_in[26];

  int E    = in_sizes[1];
  int N    = in_sizes[20];
  int K    = in_sizes[23];
  int NSEL = in_sizes[24];
  int ESEL = in_sizes[25];

  size_t N64 = (size_t)N*64;
  float* p = (float*)d_ws;
  float* node     = p; p += N64;
  float* agg      = p; p += N64;
  __hip_bfloat16* nnb = (__hip_bfloat16*)p; p += N64/2;        // bf16 new_node
  float* cw1t     = p; p += 3*4096;
  float* w2t      = p; p += 3*4096;
  float* nl2t     = p; p += 3*4096;
  float* nl3t     = p; p += 3*4096;
  float* et1t     = p; p += 128*64;
  float* nt1t     = p; p += 64*32;
  float* w1t      = p; p += 3*NC*DIM;
  __hip_bfloat16* tabb = (__hip_bfloat16*)p; p += (size_t)3*TABP*DIM; // 3 x [TABP][64] u32
  unsigned int* csr = (unsigned int*)p; p += E;
  unsigned int* rank = (unsigned int*)p; p += E;
  unsigned int* counts8 = (unsigned int*)p; p += (size_t)8*N;
  int*   total    = (int*)p; p += N;
  int*   intra    = (int*)p; p += N;
  int*   offs     = (int*)p; p += (N+1);
  int*   bsum     = (int*)p; p += ((N+255)/256 + 1);

  int nbE = (E+255)/256;
  int nbN = (N+255)/256;

  // CSR build: XCD-local atomics, then prefix/scan, then atomic-free scatter
  hipMemsetAsync(counts8, 0, (size_t)8*N*sizeof(int), stream);
  hist_rank_kernel<<<nbE, 256, 0, stream>>>(dst, counts8, rank, N, E);
  sel_mark_kernel<<<(K+255)/256, 256, 0, stream>>>(sel, rank, K);
  prep_transpose_kernel<<<48, 256, 0, stream>>>(cf_w2, nl3_w, conv_w1, nl2_w, et1_w, nt1_w,
                                                cf_w1, w2t, nl3t, cw1t, nl2t, et1t, nt1t, w1t);
  xprefix_kernel<<<nbN, 256, 0, stream>>>(counts8, total, N);
  scan1_kernel<<<nbN, 256, 0, stream>>>(total, intra, bsum, N);
  scan2_kernel<<<1, 256, 0, stream>>>(bsum, nbN);
  scan3_kernel<<<(N+256)/256, 256, 0, stream>>>(intra, bsum, offs, N, E);
  scatter_kernel<<<nbE, 256, 0, stream>>>(dist, src, dst, rank, offs, counts8, csr, N, E);
  // filter tables (3 layers, wave=row)
  table_kernel<<<(3*TABP+3)/4, 256, 0, stream>>>(edge_mask, w1t, cf_b1, w2t, cf_b2, tabb);

  int nb4  = (N+15)/16;    // 4 waves/block x 4 nodes/wave
  int nb_agg = (N+3)/4;    // 4 waves/block x 1 node/wave
  node_init_nn_kernel<<<nb4, 256, 0, stream>>>(emb, node_type, cw1t, node, nnb, N);
  for (int l=0;l<3;l++){
    agg_kernel<<<nb_agg, 256, 0, stream>>>(csr, offs,
        (const unsigned int*)(tabb + (size_t)l*TABP*2*DIM),
        (const unsigned short*)nnb, agg, N);
    if (l < 2)
      node_update_kernel<true><<<nb4, 256, 0, stream>>>(node, agg, nl2t + l*4096, nl2_b + l*64,
          nl3t + l*4096, nl3_b + l*64, cw1t + (l+1)*4096, nnb, N);
    else
      node_update_kernel<false><<<nb4, 256, 0, stream>>>(node, agg, nl2t + l*4096, nl2_b + l*64,
          nl3t + l*4096, nl3_b + l*64, nullptr, nullptr, N);
  }

  node_head_kernel<<<(NSEL+3)/4, 256, 0, stream>>>(node, node_index,
      nt1t, nt1_b, nt2_w, nt2_b, (float*)d_out, NSEL);
  edge_head_kernel<<<(ESEL+15)/16, 256, 0, stream>>>(node, source_index, target_index,
      et1t, et1_b, et2_w, et2_b, (float*)d_out + (size_t)NSEL*3, ESEL);
}

// Round 7
// 397.343 us; speedup vs baseline: 8.2421x; 1.1115x over previous
//
#include <hip/hip_runtime.h>
#include <hip/hip_bf16.h>

#define DIM 64
#define NC 50
#define TABN 4096
#define TABP (TABN + 2)   // rows 0..4096 = h at p*5/4096, row 4097 = mask row
#define EPB 4096          // edges per block in CSR build
#define NBMAX 512         // max buckets (N <= 65536)

__device__ __forceinline__ float sp_f(float x){
  // torch Softplus(beta=0.5, threshold=14): 2*log(1+exp(0.5x)), linear when 0.5*x>14
  float e = __expf(0.5f*x);
  float s = 2.0f*__logf(1.0f+e);
  return x > 28.0f ? x : s;
}

__device__ __forceinline__ float rdl(float v, int l){
  return __int_as_float(__builtin_amdgcn_readlane(__float_as_int(v), l));
}

// ---------------- CSR build: two-level LDS counting sort ----------------
// bucket = 128 consecutive dst nodes. No global per-node atomics anywhere.

// A0: global bucket histogram (LDS-staged) + zero flagbits
__global__ __launch_bounds__(256) void bhist_kernel(const int* __restrict__ dst,
                                                    unsigned int* __restrict__ gbcnt,
                                                    unsigned int* __restrict__ flagbits,
                                                    int E, int NB, int FW){
  __shared__ unsigned int cnt[NBMAX];
  int tid = threadIdx.x;
  for (int b=tid; b<NB; b+=256) cnt[b] = 0;
  __syncthreads();
  int e0 = blockIdx.x*EPB, eend = min(e0+EPB, E);
  for (int e=e0+tid; e<eend; e+=256) atomicAdd(&cnt[dst[e]>>7], 1u);
  for (int w = blockIdx.x*256+tid; w < FW; w += gridDim.x*256) flagbits[w] = 0;
  __syncthreads();
  for (int b=tid; b<NB; b+=256) if (cnt[b]) atomicAdd(&gbcnt[b], cnt[b]);
}

__global__ void sel_mark_kernel(const int* __restrict__ sel,
                                unsigned int* __restrict__ flagbits, int K){
  int id = blockIdx.x*256 + threadIdx.x;
  if (id < K){ int e = sel[id]; atomicOr(&flagbits[e>>5], 1u << (e&31)); }
}

// scan of bucket counts -> bscan (exclusive), init gcursor, offs[N]=E
__global__ __launch_bounds__(NBMAX) void bscan_kernel(const unsigned int* __restrict__ gbcnt,
                                                      unsigned int* __restrict__ bscan,
                                                      unsigned int* __restrict__ gcursor,
                                                      int* __restrict__ offs,
                                                      int NB, int N, int E){
  __shared__ unsigned int s[NBMAX];
  int tid = threadIdx.x;
  unsigned int v = (tid < NB) ? gbcnt[tid] : 0;
  s[tid] = v;
  __syncthreads();
  for (int off=1; off<NBMAX; off<<=1){
    unsigned int u = (tid >= off) ? s[tid-off] : 0;
    __syncthreads();
    s[tid] += u;
    __syncthreads();
  }
  unsigned int excl = s[tid] - v;
  if (tid < NB){ bscan[tid] = excl; gcursor[tid] = excl; }
  if (tid == NB-1) bscan[NB] = excl + v;
  if (tid == 0) offs[N] = E;
}

// A: bucket-scatter. Each block reserves per-bucket chunks (1 global atomic per
// (block,bucket)) and writes 8B entries {dstloc, (src<<16)|code} contiguously.
__global__ __launch_bounds__(256) void passA_kernel(const int* __restrict__ dst,
                                                    const int* __restrict__ src,
                                                    const float* __restrict__ dist,
                                                    const unsigned int* __restrict__ flagbits,
                                                    unsigned int* __restrict__ gcursor,
                                                    unsigned long long* __restrict__ bbuf,
                                                    int E, int NB){
  __shared__ unsigned int cnt[NBMAX];
  __shared__ unsigned int base[NBMAX];
  int tid = threadIdx.x;
  for (int b=tid; b<NB; b+=256) cnt[b] = 0;
  __syncthreads();
  int e0 = blockIdx.x*EPB, eend = min(e0+EPB, E);
  for (int e=e0+tid; e<eend; e+=256) atomicAdd(&cnt[dst[e]>>7], 1u);
  __syncthreads();
  for (int b=tid; b<NB; b+=256){
    unsigned int c = cnt[b];
    base[b] = c ? atomicAdd(&gcursor[b], c) : 0u;
    cnt[b] = 0;                       // reuse as local cursor
  }
  __syncthreads();
  for (int e=e0+tid; e<eend; e+=256){
    int d = dst[e];
    int b = d >> 7;
    unsigned int loc = atomicAdd(&cnt[b], 1u);
    float t = fminf(dist[e], 5.f) * ((float)TABN/5.0f);
    int idx = (int)(t + 0.5f); if (idx > TABN) idx = TABN;   // nearest grid point
    if ((flagbits[e>>5] >> (e&31)) & 1u) idx = TABN+1;       // mask row
    unsigned int lo = ((unsigned int)src[e] << 16) | (unsigned int)idx; // src<65536
    unsigned int hi = (unsigned int)(d & 127);
    bbuf[base[b] + loc] = ((unsigned long long)hi << 32) | lo;
  }
}

// B: one block per bucket. LDS 128-bin hist + scan -> offs[], then dense
// placement of 4B csr entries inside the bucket's contiguous window.
__global__ __launch_bounds__(256) void passB_kernel(const unsigned long long* __restrict__ bbuf,
                                                    const unsigned int* __restrict__ bscan,
                                                    int* __restrict__ offs,
                                                    unsigned int* __restrict__ csr,
                                                    int N){
  __shared__ unsigned int cnt[128];
  __shared__ unsigned int excl[128];
  int b = blockIdx.x, tid = threadIdx.x;
  unsigned int s0 = bscan[b];
  int m = (int)(bscan[b+1] - s0);
  if (tid < 128) cnt[tid] = 0;
  __syncthreads();
  for (int i=tid; i<m; i+=256)
    atomicAdd(&cnt[(unsigned int)(bbuf[s0+i] >> 32)], 1u);
  __syncthreads();
  if (tid < 128) excl[tid] = cnt[tid];
  __syncthreads();
  for (int off=1; off<128; off<<=1){
    unsigned int v = (tid < 128 && tid >= off) ? excl[tid-off] : 0;
    __syncthreads();
    if (tid < 128) excl[tid] += v;
    __syncthreads();
  }
  int node0 = b << 7;
  if (tid < 128){
    unsigned int ex = excl[tid] - cnt[tid];    // exclusive
    int n = node0 + tid;
    if (n < N) offs[n] = (int)(s0 + ex);
    excl[tid] = ex;
    cnt[tid] = 0;                              // reuse as cursor
  }
  __syncthreads();
  for (int i=tid; i<m; i+=256){
    unsigned long long v = bbuf[s0+i];
    unsigned int hi = (unsigned int)(v >> 32);
    unsigned int loc = atomicAdd(&cnt[hi], 1u);
    csr[s0 + excl[hi] + loc] = (unsigned int)v;
  }
}

// ---------------- prep: weight transposes [j][k] -> [k][j] ----------------

__global__ void prep_transpose_kernel(const float* __restrict__ cf_w2,
                                      const float* __restrict__ nl3_w,
                                      const float* __restrict__ conv_w1,
                                      const float* __restrict__ nl2_w,
                                      const float* __restrict__ et1_w,
                                      const float* __restrict__ nt1_w,
                                      const float* __restrict__ cf_w1,
                                      float* __restrict__ w2t,
                                      float* __restrict__ nl3t,
                                      float* __restrict__ cw1t,
                                      float* __restrict__ nl2t,
                                      float* __restrict__ et1t,
                                      float* __restrict__ nt1t,
                                      float* __restrict__ w1t){
  int id = blockIdx.x*256 + threadIdx.x;
  if (id < 3*4096){
    int i = id >> 12, r = id & 4095;
    int k = r >> 6, j = r & 63;
    int s = i*4096 + j*64 + k;
    w2t[id]  = cf_w2[s];
    nl3t[id] = nl3_w[s];
    cw1t[id] = conv_w1[s];
    nl2t[id] = nl2_w[s];
  }
  if (id < 128*64){
    int k = id >> 6, j = id & 63;
    et1t[id] = et1_w[j*128 + k];   // et1_w is [64][128]
  }
  if (id < 64*32){
    int k = id >> 5, j = id & 31;
    nt1t[id] = nt1_w[j*64 + k];    // nt1_w is [32][64]
  }
  if (id < 3*NC*DIM){              // cf_w1 [3][64][50] -> w1t [3][50][64]
    int l = id / (NC*DIM);
    int r = id - l*(NC*DIM);
    int m = r >> 6, k = r & 63;
    w1t[id] = cf_w1[l*DIM*NC + k*NC + m];
  }
}

// ---------------- filter table (bf16, nearest), wave = row, lane = feature ----------------

__global__ __launch_bounds__(256) void table_kernel(const float* __restrict__ edge_mask,
                                                    const float* __restrict__ w1t,   // [3][50][64]
                                                    const float* __restrict__ cf_b1,
                                                    const float* __restrict__ w2t,   // [3][64][64]
                                                    const float* __restrict__ cf_b2,
                                                    __hip_bfloat16* __restrict__ tabb){
  int row = blockIdx.x*4 + (threadIdx.x >> 6);
  if (row >= 3*TABP) return;
  int l = row / TABP, p = row - l*TABP;
  int lane = threadIdx.x & 63;
  float rbfv = 0.f;
  if (lane < NC){
    if (p == TABN+1) rbfv = edge_mask[lane];
    else {
      float d = (float)p * (5.0f/(float)TABN);
      float c = (lane == NC-1) ? 5.0f : (float)((double)lane * (5.0/49.0));
      float df = d - c;
      rbfv = __expf((float)(-1.0/(5.0/49.0)) * df * df);
    }
  }
  const float* W1 = w1t + l*NC*DIM;
  float t = cf_b1[l*DIM + lane];
  #pragma unroll 10
  for (int m=0;m<NC;m++)
    t = fmaf(rdl(rbfv, m), W1[m*64 + lane], t);
  float su = sp_f(t);
  const float* W2 = w2t + l*DIM*DIM;
  float h = cf_b2[l*DIM + lane];
  #pragma unroll 16
  for (int k=0;k<DIM;k++)
    h = fmaf(rdl(su, k), W2[k*64 + lane], h);
  tabb[((size_t)l*TABP + p)*DIM + lane] = __float2bfloat16(h);
}

// ---------------- node-side kernels (wave = 4 nodes, lane = feature) ----------------

__global__ __launch_bounds__(256) void node_init_nn_kernel(const float* __restrict__ emb,
                                                           const int* __restrict__ node_type,
                                                           const float* __restrict__ cw1t,
                                                           float* __restrict__ node,
                                                           __hip_bfloat16* __restrict__ nnb, int N){
  int wid = threadIdx.x >> 6, lane = threadIdx.x & 63;
  int n0 = (blockIdx.x*4 + wid)*4;
  if (n0 >= N) return;
  float nv[4], o[4];
  #pragma unroll
  for (int i=0;i<4;i++){
    int n = n0+i < N ? n0+i : N-1;
    nv[i] = emb[(long)node_type[n]*64 + lane];
    o[i] = 0.f;
  }
  #pragma unroll 16
  for (int k=0;k<DIM;k++){
    float w = cw1t[k*64 + lane];
    #pragma unroll
    for (int i=0;i<4;i++) o[i] = fmaf(rdl(nv[i], k), w, o[i]);
  }
  #pragma unroll
  for (int i=0;i<4;i++){
    if (n0+i < N){
      node[(long)(n0+i)*64 + lane] = nv[i];
      nnb[(long)(n0+i)*64 + lane] = __float2bfloat16(o[i]);
    }
  }
}

// gather-aggregate: wave = 1 dst node, lane = feature; 4B csr, bf16 table + new_node
__global__ __launch_bounds__(256) void agg_kernel(const unsigned int* __restrict__ csr,
                                                  const int* __restrict__ offs,
                                                  const unsigned short* __restrict__ tab,  // [TABP][64] bf16
                                                  const unsigned short* __restrict__ nnb,  // bf16 bits
                                                  float* __restrict__ agg, int N){
  int n = blockIdx.x*4 + (threadIdx.x >> 6);
  int lane = threadIdx.x & 63;
  if (n >= N) return;
  int beg = offs[n], end = offs[n+1];
  float acc = 0.f;
  for (int c = beg; c < end; c += 64){
    int m = end - c; if (m > 64) m = 64;
    unsigned int pkv = csr[c + (lane < m ? lane : 0)];   // coalesced edge-list load
    int q = 0;
    for (; q + 8 <= m; q += 8){
      #pragma unroll
      for (int u=0; u<8; u++){
        unsigned int p = (unsigned int)__builtin_amdgcn_readlane((int)pkv, q+u); // SGPR
        int idx = p & 0xFFFF, s = p >> 16;
        float a  = __uint_as_float(((unsigned int)tab[idx*64 + lane]) << 16);
        float nn = __uint_as_float(((unsigned int)nnb[(long)s*64 + lane]) << 16);
        acc = fmaf(nn, a, acc);
      }
    }
    for (; q < m; q++){
      unsigned int p = (unsigned int)__builtin_amdgcn_readlane((int)pkv, q);
      int idx = p & 0xFFFF, s = p >> 16;
      float a  = __uint_as_float(((unsigned int)tab[idx*64 + lane]) << 16);
      float nn = __uint_as_float(((unsigned int)nnb[(long)s*64 + lane]) << 16);
      acc = fmaf(nn, a, acc);
    }
  }
  agg[(long)n*64 + lane] = acc;
}

// node += sp(agg@nl2.T+b)@nl3.T+b; optionally produce next layer's new_node (bf16)
template<bool PRODUCE_NN>
__global__ __launch_bounds__(256) void node_update_kernel(float* __restrict__ node,
                                                          const float* __restrict__ agg,
                                                          const float* __restrict__ nl2t,
                                                          const float* __restrict__ nl2_b,
                                                          const float* __restrict__ nl3t,
                                                          const float* __restrict__ nl3_b,
                                                          const float* __restrict__ cw1t_next,
                                                          __hip_bfloat16* __restrict__ nnb, int N){
  int wid = threadIdx.x >> 6, lane = threadIdx.x & 63;
  int n0 = (blockIdx.x*4 + wid)*4;
  if (n0 >= N) return;
  float a[4], u[4], cacc[4];
  #pragma unroll
  for (int i=0;i<4;i++){
    int n = n0+i < N ? n0+i : N-1;
    a[i] = agg[(long)n*64 + lane];
    u[i] = nl2_b[lane];
  }
  #pragma unroll 16
  for (int k=0;k<DIM;k++){
    float w = nl2t[k*64 + lane];
    #pragma unroll
    for (int i=0;i<4;i++) u[i] = fmaf(rdl(a[i], k), w, u[i]);
  }
  #pragma unroll
  for (int i=0;i<4;i++){ u[i] = sp_f(u[i]); cacc[i] = nl3_b[lane]; }
  #pragma unroll 16
  for (int k=0;k<DIM;k++){
    float w = nl3t[k*64 + lane];
    #pragma unroll
    for (int i=0;i<4;i++) cacc[i] = fmaf(rdl(u[i], k), w, cacc[i]);
  }
  float nv[4];
  #pragma unroll
  for (int i=0;i<4;i++){
    int n = n0+i < N ? n0+i : N-1;
    nv[i] = node[(long)n*64 + lane] + cacc[i];
    if (n0+i < N) node[(long)(n0+i)*64 + lane] = nv[i];
  }
  if (PRODUCE_NN){
    float o[4];
    #pragma unroll
    for (int i=0;i<4;i++) o[i] = 0.f;
    #pragma unroll 16
    for (int k=0;k<DIM;k++){
      float w = cw1t_next[k*64 + lane];
      #pragma unroll
      for (int i=0;i<4;i++) o[i] = fmaf(rdl(nv[i], k), w, o[i]);
    }
    #pragma unroll
    for (int i=0;i<4;i++)
      if (n0+i < N) nnb[(long)(n0+i)*64 + lane] = __float2bfloat16(o[i]);
  }
}

// ---------------- heads ----------------

__global__ __launch_bounds__(256) void node_head_kernel(const float* __restrict__ node,
                                                        const int* __restrict__ nidx,
                                                        const float* __restrict__ nt1t,  // [64][32]
                                                        const float* __restrict__ nt1_b,
                                                        const float* __restrict__ nt2_w, // [3][32]
                                                        const float* __restrict__ nt2_b,
                                                        float* __restrict__ out, int NSEL){
  int r = __builtin_amdgcn_readfirstlane(blockIdx.x*4 + (threadIdx.x>>6));
  int lane = threadIdx.x & 63;
  if (r >= NSEL) return;
  long n = nidx[r];
  const float* x = node + n*64;                    // uniform -> s_loads
  float u = 0.f;
  if (lane < 32){
    u = nt1_b[lane];
    #pragma unroll
    for (int k=0;k<DIM;k++) u += x[k]*nt1t[k*32 + lane];
  }
  #pragma unroll
  for (int q=0;q<3;q++){
    float v = (lane < 32) ? u*nt2_w[q*32 + lane] : 0.f;
    #pragma unroll
    for (int o=32;o>=1;o>>=1) v += __shfl_xor(v, o);
    if (lane == 0) out[(long)r*3 + q] = nt2_b[q] + v;
  }
}

__global__ __launch_bounds__(256) void edge_head_kernel(const float* __restrict__ node,
                                                        const int* __restrict__ sidx,
                                                        const int* __restrict__ tidx,
                                                        const float* __restrict__ et1t, // [128][64]
                                                        const float* __restrict__ et1_b,
                                                        const float* __restrict__ et2_w,// [5][64]
                                                        const float* __restrict__ et2_b,
                                                        float* __restrict__ out, int ESEL){
  int wid = threadIdx.x >> 6, lane = threadIdx.x & 63;
  int r0 = (blockIdx.x*4 + wid)*4;
  if (r0 >= ESEL) return;
  float xs[4], xt[4], acc[4];
  #pragma unroll
  for (int i=0;i<4;i++){
    int r = r0+i < ESEL ? r0+i : ESEL-1;
    long s = sidx[r], t = tidx[r];
    xs[i] = node[s*64 + lane];
    xt[i] = node[t*64 + lane];
    acc[i] = et1_b[lane];
  }
  #pragma unroll 16
  for (int k=0;k<DIM;k++){
    float w1 = et1t[k*64 + lane];
    float w2 = et1t[(64+k)*64 + lane];
    #pragma unroll
    for (int i=0;i<4;i++){
      acc[i] = fmaf(rdl(xs[i], k), w1, acc[i]);
      acc[i] = fmaf(rdl(xt[i], k), w2, acc[i]);
    }
  }
  #pragma unroll
  for (int i=0;i<4;i++){
    if (r0+i >= ESEL) break;
    #pragma unroll
    for (int q=0;q<5;q++){
      float v = acc[i]*et2_w[q*64 + lane];
      #pragma unroll
      for (int o=32;o>=1;o>>=1) v += __shfl_xor(v, o);
      if (lane == 0) out[(long)(r0+i)*5 + q] = et2_b[q] + v;
    }
  }
}

// ---------------- launch ----------------

extern "C" void kernel_launch(void* const* d_in, const int* in_sizes, int n_in,
                              void* d_out, int out_size, void* d_ws, size_t ws_size,
                              hipStream_t stream){
  const float* emb      = (const float*)d_in[0];
  const float* dist     = (const float*)d_in[1];
  const float* edge_mask= (const float*)d_in[2];
  const float* conv_w1  = (const float*)d_in[3];
  const float* cf_w1    = (const float*)d_in[4];
  const float* cf_b1    = (const float*)d_in[5];
  const float* cf_w2    = (const float*)d_in[6];
  const float* cf_b2    = (const float*)d_in[7];
  const float* nl2_w    = (const float*)d_in[8];
  const float* nl2_b    = (const float*)d_in[9];
  const float* nl3_w    = (const float*)d_in[10];
  const float* nl3_b    = (const float*)d_in[11];
  const float* nt1_w    = (const float*)d_in[12];
  const float* nt1_b    = (const float*)d_in[13];
  const float* nt2_w    = (const float*)d_in[14];
  const float* nt2_b    = (const float*)d_in[15];
  const float* et1_w    = (const float*)d_in[16];
  const float* et1_b    = (const float*)d_in[17];
  const float* et2_w    = (const float*)d_in[18];
  const float* et2_b    = (const float*)d_in[19];
  const int* node_type  = (const int*)d_in[20];
  const int* src        = (const int*)d_in[21];
  const int* dst        = (const int*)d_in[22];
  const int* sel        = (const int*)d_in[23];
  const int* node_index = (const int*)d_in[24];
  const int* source_index = (const int*)d_in[25];
  const int* target_index = (const int*)d_in[26];

  int E    = in_sizes[1];
  int N    = in_sizes[20];
  int K    = in_sizes[23];
  int NSEL = in_sizes[24];
  int ESEL = in_sizes[25];

  int NB  = (N + 127) >> 7;           // buckets of 128 nodes (<= NBMAX for N<=65536)
  int FW  = (E + 31) >> 5;            // flag words
  int nbE = (E + EPB - 1) / EPB;      // CSR-build blocks

  size_t N64 = (size_t)N*64;
  // bbuf (E u64) first for 8B alignment; agg aliases it (lifetimes disjoint:
  // bbuf dead after passB; agg first written in layer-0 agg_kernel).
  unsigned long long* bbuf = (unsigned long long*)d_ws;
  float* agg = (float*)d_ws;
  size_t aggsz = ((size_t)2*E > N64) ? (size_t)2*E : N64;   // float units
  float* p = (float*)d_ws + aggsz;
  float* node     = p; p += N64;
  __hip_bfloat16* nnb = (__hip_bfloat16*)p; p += N64/2;     // bf16 new_node
  float* cw1t     = p; p += 3*4096;
  float* w2t      = p; p += 3*4096;
  float* nl2t     = p; p += 3*4096;
  float* nl3t     = p; p += 3*4096;
  float* et1t     = p; p += 128*64;
  float* nt1t     = p; p += 64*32;
  float* w1t      = p; p += 3*NC*DIM;
  __hip_bfloat16* tabb = (__hip_bfloat16*)p; p += (size_t)3*TABP*DIM/2;
  unsigned int* csr      = (unsigned int*)p; p += E;
  unsigned int* flagbits = (unsigned int*)p; p += FW;
  unsigned int* gbcnt    = (unsigned int*)p; p += NB;
  unsigned int* bscan    = (unsigned int*)p; p += NB+1;
  unsigned int* gcursor  = (unsigned int*)p; p += NB;
  int* offs              = (int*)p; p += N+1;

  // CSR build: two-level LDS counting sort
  hipMemsetAsync(gbcnt, 0, (size_t)NB*sizeof(int), stream);
  bhist_kernel<<<nbE, 256, 0, stream>>>(dst, gbcnt, flagbits, E, NB, FW);
  sel_mark_kernel<<<(K+255)/256, 256, 0, stream>>>(sel, flagbits, K);
  prep_transpose_kernel<<<48, 256, 0, stream>>>(cf_w2, nl3_w, conv_w1, nl2_w, et1_w, nt1_w,
                                                cf_w1, w2t, nl3t, cw1t, nl2t, et1t, nt1t, w1t);
  bscan_kernel<<<1, NBMAX, 0, stream>>>(gbcnt, bscan, gcursor, offs, NB, N, E);
  passA_kernel<<<nbE, 256, 0, stream>>>(dst, src, dist, flagbits, gcursor, bbuf, E, NB);
  passB_kernel<<<NB, 256, 0, stream>>>(bbuf, bscan, offs, csr, N);
  // filter tables (3 layers, wave=row, nearest-neighbor bf16)
  table_kernel<<<(3*TABP+3)/4, 256, 0, stream>>>(edge_mask, w1t, cf_b1, w2t, cf_b2, tabb);

  int nb4  = (N+15)/16;    // 4 waves/block x 4 nodes/wave
  int nb_agg = (N+3)/4;    // 4 waves/block x 1 node/wave
  node_init_nn_kernel<<<nb4, 256, 0, stream>>>(emb, node_type, cw1t, node, nnb, N);
  for (int l=0;l<3;l++){
    agg_kernel<<<nb_agg, 256, 0, stream>>>(csr, offs,
        (const unsigned short*)(tabb + (size_t)l*TABP*DIM),
        (const unsigned short*)nnb, agg, N);
    if (l < 2)
      node_update_kernel<true><<<nb4, 256, 0, stream>>>(node, agg, nl2t + l*4096, nl2_b + l*64,
          nl3t + l*4096, nl3_b + l*64, cw1t + (l+1)*4096, nnb, N);
    else
      node_update_kernel<false><<<nb4, 256, 0, stream>>>(node, agg, nl2t + l*4096, nl2_b + l*64,
          nl3t + l*4096, nl3_b + l*64, nullptr, nullptr, N);
  }

  node_head_kernel<<<(NSEL+3)/4, 256, 0, stream>>>(node, node_index,
      nt1t, nt1_b, nt2_w, nt2_b, (float*)d_out, NSEL);
  edge_head_kernel<<<(ESEL+15)/16, 256, 0, stream>>>(node, source_index, target_index,
      et1t, et1_b, et2_w, et2_b, (float*)d_out + (size_t)NSEL*3, ESEL);
}